// Round 14
// baseline (754.113 us; speedup 1.0000x reference)
//
#include <hip/hip_runtime.h>

#define TPB 256

typedef _Float16 f16;
typedef __attribute__((ext_vector_type(8))) _Float16 f16x8;
typedef __attribute__((ext_vector_type(16))) float f32x16;

#define GLD_LDS(g, l) __builtin_amdgcn_global_load_lds( \
    (const __attribute__((address_space(1))) void*)(g), \
    (__attribute__((address_space(3))) void*)(l), 16, 0, 0)

// ---------- merged transpose-cvt (aspp + low_level) + global pool tail ----------
__global__ __launch_bounds__(TPB)
void tcz_k(const float* __restrict__ aspp, const float* __restrict__ ll,
           f16* __restrict__ Xa, f16* __restrict__ Xll, float* __restrict__ gp)
{
    const int bid = blockIdx.x;
    const int tid = threadIdx.x;
    __shared__ float t32[32 * 33];
    __shared__ float red[4];
    if (bid >= 12816) {
        const int bc = bid - 12816;
        const float* p = aspp + (size_t)bc * 1089;
        float s = 0.f;
        for (int i = tid; i < 1089; i += TPB) s += p[i];
#pragma unroll
        for (int off = 32; off > 0; off >>= 1) s += __shfl_down(s, off, 64);
        if ((tid & 63) == 0) red[tid >> 6] = s;
        __syncthreads();
        if (tid == 0) gp[bc] = (red[0] + red[1] + red[2] + red[3]) * (1.0f / 1089.0f);
        return;
    }
    const float* src; f16* dst; int C, HW, ldk, pT, cT, bb;
    if (bid < 4480) {
        src = aspp; dst = Xa; C = 2048; HW = 1089; ldk = 2048;
        pT = bid % 35; cT = (bid / 35) % 64; bb = bid / 2240;
    } else {
        const int b2 = bid - 4480;
        src = ll; dst = Xll; C = 256; HW = 16641; ldk = 256;
        pT = b2 % 521; cT = (b2 / 521) % 8; bb = b2 / 4168;
    }
#pragma unroll
    for (int pass = 0; pass < 4; ++pass) {
        const int ch = tid / 32 + pass * 8;
        const int px = tid % 32;
        const int c = cT * 32 + ch, p = pT * 32 + px;
        float v = 0.f;
        if (c < C && p < HW) v = src[((long)bb * C + c) * HW + p];
        t32[ch * 33 + px] = v;
    }
    __syncthreads();
#pragma unroll
    for (int pass = 0; pass < 4; ++pass) {
        const int px = tid / 32 + pass * 8;
        const int ch = tid % 32;
        const int p = pT * 32 + px, c = cT * 32 + ch;
        if (p < HW && c < C)
            dst[((long)bb * HW + p) * ldk + c] = (f16)t32[ch * 33 + px];
    }
}

// ---------- band-aware partial-sum + relu + transpose: BRpart(10 slices) -> BRX2 ----------
__global__ __launch_bounds__(TPB)
void tcr_k(const f16* __restrict__ part, f16* __restrict__ dst)
{
    __shared__ float t32[32 * 33];
    const int pT = blockIdx.x, cT = blockIdx.y, bb = blockIdx.z;
    const int tid = threadIdx.x;
    const int br = cT >> 3;
    const f16* pb = part + (long)bb * 2787840;
#pragma unroll
    for (int pass = 0; pass < 4; ++pass) {
        const int ch = tid / 32 + pass * 8;
        const int px = tid % 32;
        const int c = cT * 32 + ch;
        const int cl = c & 255;
        const int p = pT * 32 + px;
        float v = 0.f;
        if (p < 1089) {
            if (br == 0) {
                v = (float)pb[(long)cl * 1089 + p];
            } else {
                const int dl = 6 * br;
                const int y = p / 33;
                const int s0 = 1 + 3 * (br - 1);
#pragma unroll
                for (int g = 0; g < 3; ++g) {
                    const int dy0 = (g - 1) * dl;
                    const int yLo = max(0, -dy0), yHi = min(33, 33 - dy0);
                    if (y >= yLo && y < yHi)
                        v += (float)pb[((long)(s0 + g) * 256 + cl) * 1089 + p];
                }
            }
            v = fmaxf(v, 0.f);
        }
        t32[ch * 33 + px] = v;
    }
    __syncthreads();
#pragma unroll
    for (int pass = 0; pass < 4; ++pass) {
        const int px = tid / 32 + pass * 8;
        const int ch = tid % 32;
        const int p = pT * 32 + px, c = cT * 32 + ch;
        if (p < 1089)
            dst[((long)bb * 1089 + p) * 1024 + c] = (f16)t32[ch * 33 + px];
    }
}

// ---------- pool-branch GEMVs ----------
__global__ __launch_bounds__(TPB)
void gemv1_k(const float* __restrict__ pw0, const float* __restrict__ pw1,
             const float* __restrict__ gp, float* __restrict__ gpr2)
{
    const int bh = blockIdx.x & 3;
    const int cgrp = blockIdx.x >> 2;
    const int b = bh & 1;
    const float* w = (bh >> 1) ? pw1 : pw0;
    const int c = cgrp * 16 + (threadIdx.x >> 4);
    const int kl = threadIdx.x & 15;
    const float* g = gp + (size_t)b * 2048;
    float4 acc = {0.f, 0.f, 0.f, 0.f};
    for (int k = kl * 4; k < 2048; k += 64) {
        const float4 wv = *(const float4*)&w[(size_t)c * 2048 + k];
        const float4 gv = *(const float4*)&g[k];
        acc.x = fmaf(wv.x, gv.x, acc.x);
        acc.y = fmaf(wv.y, gv.y, acc.y);
        acc.z = fmaf(wv.z, gv.z, acc.z);
        acc.w = fmaf(wv.w, gv.w, acc.w);
    }
    float s = (acc.x + acc.y) + (acc.z + acc.w);
#pragma unroll
    for (int o = 8; o; o >>= 1) s += __shfl_xor(s, o, 16);
    if (kl == 0) gpr2[bh * 256 + c] = fmaxf(s, 0.f);
}

__global__ __launch_bounds__(TPB)
void gemv2_k(const float* __restrict__ ap0, const float* __restrict__ ap1,
             const float* __restrict__ gpr2, float* __restrict__ gpc2)
{
    const int bh = blockIdx.x & 3;
    const int cgrp = blockIdx.x >> 2;
    const float* w = (bh >> 1) ? ap1 : ap0;
    const int c = cgrp * 16 + (threadIdx.x >> 4);
    const int kl = threadIdx.x & 15;
    const float* g = gpr2 + bh * 256;
    float4 acc = {0.f, 0.f, 0.f, 0.f};
    for (int k = kl * 4; k < 256; k += 64) {
        const float4 wv = *(const float4*)&w[(size_t)c * 1280 + 1024 + k];
        const float4 gv = *(const float4*)&g[k];
        acc.x = fmaf(wv.x, gv.x, acc.x);
        acc.y = fmaf(wv.y, gv.y, acc.y);
        acc.z = fmaf(wv.z, gv.z, acc.z);
        acc.w = fmaf(wv.w, gv.w, acc.w);
    }
    float s = (acc.x + acc.y) + (acc.z + acc.w);
#pragma unroll
    for (int o = 8; o; o >>= 1) s += __shfl_xor(s, o, 16);
    if (kl == 0) gpc2[bh * 256 + c] = s;
}

// ---------- mega pack: 14 weight-pack jobs + guard zero ----------
struct PackJob { const float* w; f16* dst; int Cout, CinUse, CinSrc, T, coP, KB, start; };
struct PackParams { PackJob j[14]; };

__global__ __launch_bounds__(TPB)
void packw_mega(PackParams P, float* __restrict__ guard)
{
    const int bid = blockIdx.x;
    const int tid = threadIdx.x;
    if (bid >= 4832) {
        float4 zv = {0.f, 0.f, 0.f, 0.f};
        float4* p = (float4*)(guard + tid * 16);
        p[0] = zv; p[1] = zv; p[2] = zv; p[3] = zv;
        return;
    }
    int ji = 0;
#pragma unroll
    for (int t = 1; t < 14; ++t) if (bid >= P.j[t].start) ji = t;
    PackJob J;
    switch (ji) {
        case 0:  J = P.j[0];  break;
        case 1:  J = P.j[1];  break;
        case 2:  J = P.j[2];  break;
        case 3:  J = P.j[3];  break;
        case 4:  J = P.j[4];  break;
        case 5:  J = P.j[5];  break;
        case 6:  J = P.j[6];  break;
        case 7:  J = P.j[7];  break;
        case 8:  J = P.j[8];  break;
        case 9:  J = P.j[9];  break;
        case 10: J = P.j[10]; break;
        case 11: J = P.j[11]; break;
        case 12: J = P.j[12]; break;
        default: J = P.j[13]; break;
    }
    const int local = bid - J.start;
    const int kb = local % J.KB;
    const int coT = local / J.KB;
    const int T = J.T;
    __shared__ float tile[16 * 577];
    const int RL = 64 * T;
    const int n = 16 * RL;
    for (int idx = tid; idx < n; idx += TPB) {
        const int row = idx / RL;
        const int jj = idx - row * RL;
        const int co = coT * 16 + row;
        const int k = kb * 64 + jj / T;
        float v = 0.f;
        if (co < J.Cout && k < J.CinUse)
            v = J.w[((long)co * J.CinSrc + kb * 64) * T + jj];
        tile[row * 577 + jj] = v;
    }
    __syncthreads();
    const int nst = 128 * T;
    for (int idx = tid; idx < nst; idx += TPB) {
        const int g = idx & 7;
        const int t = (idx >> 3) % T;
        const int co = idx / (8 * T);
        f16x8 hv;
#pragma unroll
        for (int e = 0; e < 8; ++e)
            hv[e] = (f16)tile[co * 577 + (g * 8 + e) * T + t];
        *(f16x8*)&J.dst[(((long)t * J.KB + kb) * J.coP + coT * 16 + co) * 64 + g * 8] = hv;
    }
}

// ---------- merged mconv: ASPP z=10 row-groups (720 blocks) + low-level conv (524) ----------
// R10-proven structure: 32KB single buffer, __syncthreads, 4 blocks/CU.
__global__ __launch_bounds__(TPB, 4)
void mconv2_k(const f16* __restrict__ Xa, const f16* __restrict__ Xll,
              const f16* __restrict__ Wa, const f16* __restrict__ Wl,
              const f16* __restrict__ guard, f16* __restrict__ brp,
              f16* __restrict__ ccx)
{
    __shared__ char SH[32768];
    const int tid = threadIdx.x;

    int wg;
    {
        const int orig = blockIdx.x, nwg = gridDim.x;
        const int q = nwg >> 3, r = nwg & 7;
        const int xcd = orig & 7, off = orig >> 3;
        wg = (xcd < r ? xcd * (q + 1) : r * (q + 1) + (xcd - r) * q) + off;
    }

    const f16 *X, *Wbase;
    f16* outp;
    int Cinp, W, H, NP, kbPerTap, coP, Cout, co0, p0, pMax, outmode;
    int tapStart, tapCnt, kss, dl;
    long ooff;
    if (wg < 720) {
        const int mt = wg & 1;
        const int bh = (wg >> 1) & 3;
        const int z  = (wg >> 3) % 10;
        const int nt = wg / 80;
        const int b = bh & 1, hd = bh >> 1;
        Cinp = 2048; H = 33; W = 33; NP = 1089; kbPerTap = 32;
        coP = 256; Cout = 256; co0 = mt * 128;
        int br, grp;
        if (z == 0) { br = 0; grp = 1; kss = 1; dl = 1; tapStart = 0; tapCnt = 1; }
        else { br = 1 + (z - 1) / 3; grp = (z - 1) % 3;
               kss = 3; dl = 6 * br; tapStart = grp * 3; tapCnt = 3; }
        const long woff = (long)hd * 14680064L +
            (br == 0 ? 0L : (br == 1 ? 524288L : (br == 2 ? 5242880L : 9961472L)));
        Wbase = Wa + woff;
        X = Xa + (long)b * (1089L * 2048);
        const int dy0 = (kss == 1) ? 0 : (grp - 1) * dl;
        const int yLo = max(0, -dy0), yHi = min(33, 33 - dy0);
        p0 = yLo * 33 + nt * 128;
        pMax = yHi * 33;
        if (p0 >= pMax) return;
        outp = brp;
        ooff = (long)(2 * hd + b) * 2787840L + (long)z * 278784L;
        outmode = 1;
    } else {
        const int local = wg - 720;
        const int bh = local & 3;
        const int nt = local >> 2;
        const int b = bh & 1, hd = bh >> 1;
        Cinp = 256; H = 129; W = 129; NP = 16641; kbPerTap = 4;
        coP = 128; Cout = 48; co0 = 0;
        kss = 1; dl = 1; tapStart = 0; tapCnt = 1;
        p0 = nt * 128; pMax = 16641;
        if (p0 >= pMax) return;
        X = Xll + (long)b * (16641L * 256);
        Wbase = Wl + (long)hd * 32768L;
        outp = ccx;
        ooff = (long)(2 * hd + b) * 5325120L;
        outmode = 3;
    }
    const int half = kss >> 1;

    // ---- staging geometry ----
    const int srow = tid >> 3;
    const int sslot = tid & 7;
    int aofs[4];
#pragma unroll
    for (int q = 0; q < 4; ++q) {
        const int row = q * 32 + srow;
        aofs[q] = row * 64 + ((sslot ^ (row & 7)) << 3);
    }
    const long coStr = (long)coP * 64;

    // ---- compute roles ----
    const int lane = tid & 63, wid = tid >> 6;
    const int wm = wid >> 1, wn = wid & 1;
    const int r32 = lane & 31, hh = lane >> 5;
    const int arow0 = wm * 64 + r32, arow1 = arow0 + 32;
    const int brow0 = wn * 64 + r32, brow1 = brow0 + 32;
    const int abase0 = arow0 * 128, abase1 = arow1 * 128;
    const int bbase0 = 16384 + brow0 * 128, bbase1 = 16384 + brow1 * 128;
    const int ax0 = (arow0 & 7), ax1 = (arow1 & 7);
    const int bx0 = (brow0 & 7), bx1 = (brow1 & 7);

    f32x16 acc[2][2];
#pragma unroll
    for (int i = 0; i < 2; ++i)
#pragma unroll
        for (int j = 0; j < 2; ++j) acc[i][j] = (f32x16)(0.f);

    const f16* Pr[4];
    for (int ti = 0; ti < tapCnt; ++ti) {
        const int tp = tapStart + ti;
        const int ky = tp / kss, kx = tp - ky * kss;
        const int dy = (ky - half) * dl, dx = (kx - half) * dl;
#pragma unroll
        for (int q = 0; q < 4; ++q) {
            const int row = q * 32 + srow;
            const int p = p0 + row;
            bool v = p < pMax;
            const int py = v ? p / W : 0;
            const int px = v ? p - py * W : 0;
            const int sy = py + dy, sx = px + dx;
            v = v && ((unsigned)sy < (unsigned)H) && ((unsigned)sx < (unsigned)W);
            const int swz = (sslot ^ (row & 7)) << 3;
            Pr[q] = v ? (X + ((long)sy * W + sx) * Cinp + swz) : (guard + swz);
        }
        const f16* Wt = Wbase + ((long)tp * kbPerTap * coP + (long)co0) * 64;
        for (int kb = 0; kb < kbPerTap; ++kb) {
            __syncthreads();
            const f16* wsrc = Wt + (long)kb * coStr;
            const long kcol = (long)kb << 6;
            GLD_LDS(wsrc + aofs[0], SH + (tid << 4));
            GLD_LDS(wsrc + aofs[1], SH + 4096 + (tid << 4));
            GLD_LDS(wsrc + aofs[2], SH + 8192 + (tid << 4));
            GLD_LDS(wsrc + aofs[3], SH + 12288 + (tid << 4));
            GLD_LDS(Pr[0] + kcol, SH + 16384 + (tid << 4));
            GLD_LDS(Pr[1] + kcol, SH + 20480 + (tid << 4));
            GLD_LDS(Pr[2] + kcol, SH + 24576 + (tid << 4));
            GLD_LDS(Pr[3] + kcol, SH + 28672 + (tid << 4));
            __syncthreads();
            __builtin_amdgcn_s_setprio(1);
#pragma unroll
            for (int kh = 0; kh < 4; ++kh) {
                const int g = kh * 2 + hh;
                const f16x8 a0 = *(const f16x8*)(SH + abase0 + ((g ^ ax0) << 4));
                const f16x8 a1 = *(const f16x8*)(SH + abase1 + ((g ^ ax1) << 4));
                const f16x8 b0 = *(const f16x8*)(SH + bbase0 + ((g ^ bx0) << 4));
                const f16x8 b1 = *(const f16x8*)(SH + bbase1 + ((g ^ bx1) << 4));
                acc[0][0] = __builtin_amdgcn_mfma_f32_32x32x16_f16(a0, b0, acc[0][0], 0, 0, 0);
                acc[0][1] = __builtin_amdgcn_mfma_f32_32x32x16_f16(a0, b1, acc[0][1], 0, 0, 0);
                acc[1][0] = __builtin_amdgcn_mfma_f32_32x32x16_f16(a1, b0, acc[1][0], 0, 0, 0);
                acc[1][1] = __builtin_amdgcn_mfma_f32_32x32x16_f16(a1, b1, acc[1][1], 0, 0, 0);
            }
            __builtin_amdgcn_s_setprio(0);
        }
    }

#pragma unroll
    for (int mi = 0; mi < 2; ++mi)
#pragma unroll
    for (int ni = 0; ni < 2; ++ni)
#pragma unroll
    for (int j = 0; j < 16; ++j) {
        const int m = wm * 64 + mi * 32 + 4 * hh + (j & 3) + 8 * (j >> 2);
        const int n = wn * 64 + ni * 32 + r32;
        const int co = co0 + m;
        const int p = p0 + n;
        if (co < Cout && p < pMax) {
            const float v = acc[mi][ni][j];
            if (outmode == 1)
                outp[ooff + (long)co * NP + p] = (f16)v;
            else
                outp[ooff + (long)p * 320 + co] = (f16)fmaxf(v, 0.f);
        }
    }
}

// ---------- MFMA implicit-GEMM conv (R10 structure; aproj + cw1) ----------
template <int OUTMODE, int RELUOUT, int BIAS>
__global__ __launch_bounds__(TPB, 4)
void mconv(const f16* __restrict__ X, const f16* __restrict__ Wp,
           const f16* __restrict__ guard, void* __restrict__ out_,
           const float* __restrict__ gpc,
           int Cinp, int Cout, int H, int W, int kss, int dl,
           int kbPerTap, int tapCnt,
           long xHstr, long wHstr, long oHstr, long outBStride,
           int coP, int ldOut, int NM, int NBH, int NZ)
{
    __shared__ char SH[32768];
    const int tid = threadIdx.x;

    int wg;
    {
        const int orig = blockIdx.x, nwg = gridDim.x;
        const int q = nwg >> 3, r = nwg & 7;
        const int xcd = orig & 7, off = orig >> 3;
        wg = (xcd < r ? xcd * (q + 1) : r * (q + 1) + (xcd - r) * q) + off;
    }
    const int mt = wg % NM; wg /= NM;
    const int bh = wg % NBH; wg /= NBH;
    const int nt = wg / NZ;
    const int b = bh & 1, hd = bh >> 1;
    const int co0 = mt * 128;
    const int NP = H * W;
    const long xBstr = (long)NP * Cinp;

    const long woff = (long)hd * wHstr, ooff = (long)hd * oHstr;
    const int p0 = nt * 128, pMax = NP;
    if (p0 >= pMax) return;
    const int half = kss >> 1;
    const int y0t = p0 / W, y1t = min(p0 + 127, pMax - 1) / W;

    int taps[9]; int nval = 0;
    for (int t = 0; t < tapCnt; ++t) {
        const int ky = t / kss;
        const int dyv = (ky - half) * dl;
        if (y1t + dyv >= 0 && y0t + dyv < H) taps[nval++] = t;
    }
    if (nval == 0) return;

    const int srow = tid >> 3;
    const int sslot = tid & 7;
    int aofs[4];
#pragma unroll
    for (int q = 0; q < 4; ++q) {
        const int row = q * 32 + srow;
        aofs[q] = row * 64 + ((sslot ^ (row & 7)) << 3);
    }
    const long coStr = (long)coP * 64;

    const int lane = tid & 63, wid = tid >> 6;
    const int wm = wid >> 1, wn = wid & 1;
    const int r32 = lane & 31, hh = lane >> 5;
    const int arow0 = wm * 64 + r32, arow1 = arow0 + 32;
    const int brow0 = wn * 64 + r32, brow1 = brow0 + 32;
    const int abase0 = arow0 * 128, abase1 = arow1 * 128;
    const int bbase0 = 16384 + brow0 * 128, bbase1 = 16384 + brow1 * 128;
    const int ax0 = (arow0 & 7), ax1 = (arow1 & 7);
    const int bx0 = (brow0 & 7), bx1 = (brow1 & 7);

    f32x16 acc[2][2];
#pragma unroll
    for (int i = 0; i < 2; ++i)
#pragma unroll
        for (int j = 0; j < 2; ++j) acc[i][j] = (f32x16)(0.f);

    const f16* Pr[4];
    for (int ti = 0; ti < nval; ++ti) {
        const int tp = taps[ti];
        const int ky = tp / kss, kx = tp - ky * kss;
        const int dy = (ky - half) * dl, dx = (kx - half) * dl;
#pragma unroll
        for (int q = 0; q < 4; ++q) {
            const int row = q * 32 + srow;
            const int p = p0 + row;
            bool v = p < pMax;
            const int py = v ? p / W : 0;
            const int px = v ? p - py * W : 0;
            const int sy = py + dy, sx = px + dx;
            v = v && ((unsigned)sy < (unsigned)H) && ((unsigned)sx < (unsigned)W);
            const int swz = (sslot ^ (row & 7)) << 3;
            Pr[q] = v ? (X + (long)b * xBstr + (long)hd * xHstr
                           + ((long)sy * W + sx) * (long)Cinp + swz)
                      : (guard + swz);
        }
        const f16* Wt = Wp + woff + ((long)tp * kbPerTap * coP + (long)co0) * 64;
        for (int kb = 0; kb < kbPerTap; ++kb) {
            __syncthreads();
            const f16* wsrc = Wt + (long)kb * coStr;
            const long kcol = (long)kb << 6;
            GLD_LDS(wsrc + aofs[0], SH + (tid << 4));
            GLD_LDS(wsrc + aofs[1], SH + 4096 + (tid << 4));
            GLD_LDS(wsrc + aofs[2], SH + 8192 + (tid << 4));
            GLD_LDS(wsrc + aofs[3], SH + 12288 + (tid << 4));
            GLD_LDS(Pr[0] + kcol, SH + 16384 + (tid << 4));
            GLD_LDS(Pr[1] + kcol, SH + 20480 + (tid << 4));
            GLD_LDS(Pr[2] + kcol, SH + 24576 + (tid << 4));
            GLD_LDS(Pr[3] + kcol, SH + 28672 + (tid << 4));
            __syncthreads();
            __builtin_amdgcn_s_setprio(1);
#pragma unroll
            for (int kh = 0; kh < 4; ++kh) {
                const int g = kh * 2 + hh;
                const f16x8 a0 = *(const f16x8*)(SH + abase0 + ((g ^ ax0) << 4));
                const f16x8 a1 = *(const f16x8*)(SH + abase1 + ((g ^ ax1) << 4));
                const f16x8 b0 = *(const f16x8*)(SH + bbase0 + ((g ^ bx0) << 4));
                const f16x8 b1 = *(const f16x8*)(SH + bbase1 + ((g ^ bx1) << 4));
                acc[0][0] = __builtin_amdgcn_mfma_f32_32x32x16_f16(a0, b0, acc[0][0], 0, 0, 0);
                acc[0][1] = __builtin_amdgcn_mfma_f32_32x32x16_f16(a0, b1, acc[0][1], 0, 0, 0);
                acc[1][0] = __builtin_amdgcn_mfma_f32_32x32x16_f16(a1, b0, acc[1][0], 0, 0, 0);
                acc[1][1] = __builtin_amdgcn_mfma_f32_32x32x16_f16(a1, b1, acc[1][1], 0, 0, 0);
            }
            __builtin_amdgcn_s_setprio(0);
        }
    }

    const long outB = (long)b * outBStride + ooff;
    const float* gpcp = BIAS ? (gpc + (long)(b + 2 * hd) * 256) : nullptr;
#pragma unroll
    for (int mi = 0; mi < 2; ++mi)
#pragma unroll
    for (int ni = 0; ni < 2; ++ni)
#pragma unroll
    for (int j = 0; j < 16; ++j) {
        const int m = wm * 64 + mi * 32 + 4 * hh + (j & 3) + 8 * (j >> 2);
        const int n = wn * 64 + ni * 32 + r32;
        const int co = co0 + m;
        const int p = p0 + n;
        if (co < Cout && p < pMax) {
            float v = acc[mi][ni][j];
            if (BIAS) v += gpcp[co];
            if (RELUOUT) v = fmaxf(v, 0.f);
            if (OUTMODE == 1) ((f16*)out_)[outB + (long)co * NP + p] = (f16)v;
            else              ((f16*)out_)[outB + (long)p * ldOut + co] = (f16)v;
        }
    }
}

// ---------- upsample 33->129 (4 slots) + CCX2 pad-zero ----------
__global__ __launch_bounds__(TPB)
void ups2pad_k(const f16* __restrict__ ybx, f16* __restrict__ ccx)
{
    const int idx = blockIdx.x * TPB + threadIdx.x;
    if (idx >= 4 * 16641 * 34) return;
    const int s = idx / (16641 * 34);
    const int rem = idx - s * (16641 * 34);
    const int p = rem / 34;
    const int cg = rem - p * 34;
    if (cg >= 32) {
        f16x8 zv = (f16x8)(f16)0.f;
        *(f16x8*)(ccx + ((long)s * 16641 + p) * 320 + 304 + (cg - 32) * 8) = zv;
        return;
    }
    const int oy = p / 129, ox = p % 129;
    const float sc = 33.0f / 129.0f;
    const float sx = (ox + 0.5f) * sc - 0.5f;
    const float sy = (oy + 0.5f) * sc - 0.5f;
    int ix0 = (int)floorf(sx), iy0 = (int)floorf(sy);
    const float fx = sx - ix0, fy = sy - iy0;
    int ix1 = min(32, max(0, ix0 + 1)); ix0 = min(32, max(0, ix0));
    int iy1 = min(32, max(0, iy0 + 1)); iy0 = min(32, max(0, iy0));
    const f16* base = ybx + (long)s * 1089 * 256 + cg * 8;
    const f16x8 v00 = *(const f16x8*)(base + ((long)iy0 * 33 + ix0) * 256);
    const f16x8 v01 = *(const f16x8*)(base + ((long)iy0 * 33 + ix1) * 256);
    const f16x8 v10 = *(const f16x8*)(base + ((long)iy1 * 33 + ix0) * 256);
    const f16x8 v11 = *(const f16x8*)(base + ((long)iy1 * 33 + ix1) * 256);
    f16x8 r;
#pragma unroll
    for (int e = 0; e < 8; ++e) {
        const float a0 = (float)v00[e] + ((float)v01[e] - (float)v00[e]) * fx;
        const float a1 = (float)v10[e] + ((float)v11[e] - (float)v10[e]) * fx;
        r[e] = (f16)(a0 + (a1 - a0) * fy);
    }
    *(f16x8*)(ccx + ((long)s * 16641 + p) * 320 + 48 + cg * 8) = r;
}

// ---------- cw2 1x1 conv, both heads, raw weights ----------
__global__ __launch_bounds__(TPB)
void conv1x1_m(const f16* __restrict__ c1o2,
               const float* __restrict__ w0, const float* __restrict__ w1,
               const float* __restrict__ b0, const float* __restrict__ b1,
               float* __restrict__ xb2)
{
    const int h = blockIdx.z;
    const int nc = h ? 17 : 16;
    const float* w = h ? w1 : w0;
    const float* bias = h ? b1 : b0;
    __shared__ float wsm[256 * 17];
    __shared__ float bsm[17];
    const int tid = threadIdx.x;
    for (int l = tid; l < 256 * 17; l += TPB) {
        const int k = l / 17, c = l - k * 17;
        wsm[l] = (c < nc) ? w[(size_t)c * 256 + k] : 0.f;
    }
    if (tid < nc) bsm[tid] = bias[tid];
    __syncthreads();
    const int b = blockIdx.y;
    const int p = blockIdx.x * TPB + tid;
    if (p >= 16641) return;
    const f16* inB = c1o2 + (long)h * 8520192 + (long)b * 4260096 + p;
    float acc[17];
#pragma unroll
    for (int c = 0; c < 17; ++c) acc[c] = 0.f;
    for (int k = 0; k < 256; ++k) {
        const float x = (float)inB[(size_t)k * 16641];
#pragma unroll
        for (int c = 0; c < 17; ++c) acc[c] = fmaf(wsm[k * 17 + c], x, acc[c]);
    }
    float* oB = xb2 + (h ? 532512L : 0L) + ((long)b * nc) * 16641 + p;
#pragma unroll
    for (int c = 0; c < 17; ++c)
        if (c < nc) oB[(size_t)c * 16641] = acc[c] + bsm[c];
}

// ---------- final: 129->513 bilinear + logits + NHWC features, both heads ----------
__global__ __launch_bounds__(TPB)
void final_m(const float* __restrict__ xb2, float* __restrict__ o)
{
    const int idx = blockIdx.x * TPB + threadIdx.x;
    if (idx >= 2 * 526338) return;
    const int hd = idx / 526338;
    int r = idx - hd * 526338;
    const int ox = r % 513; r /= 513;
    const int oy = r % 513;
    const int b = r / 513;
    const int nc = hd ? 17 : 16;
    const long HW = 513L * 513L;
    const float sc = 129.0f / 513.0f;
    const float sx = (ox + 0.5f) * sc - 0.5f;
    const float sy = (oy + 0.5f) * sc - 0.5f;
    int ix0 = (int)floorf(sx), iy0 = (int)floorf(sy);
    const float fx = sx - ix0, fy = sy - iy0;
    int ix1 = min(128, max(0, ix0 + 1)); ix0 = min(128, max(0, ix0));
    int iy1 = min(128, max(0, iy0 + 1)); iy0 = min(128, max(0, iy0));
    const float* xb = xb2 + (hd ? 532512L : 0L) + (size_t)b * nc * 16641;
    const int i00 = iy0 * 129 + ix0, i01 = iy0 * 129 + ix1;
    const int i10 = iy1 * 129 + ix0, i11 = iy1 * 129 + ix1;
    float* logits = o + (hd ? 8421408L : 0L);
    float* feats  = o + (hd ? 25791107L : 17369699L);
    float v[17];
    float ss = 0.f;
#pragma unroll
    for (int c = 0; c < 17; ++c) {
        if (c < nc) {
            const float* s = xb + (size_t)c * 16641;
            const float a0 = s[i00] + (s[i01] - s[i00]) * fx;
            const float a1 = s[i10] + (s[i11] - s[i10]) * fx;
            const float vv = a0 + (a1 - a0) * fy;
            v[c] = vv;
            ss = fmaf(vv, vv, ss);
        }
    }
    const long pix = (long)oy * 513 + ox;
#pragma unroll
    for (int c = 0; c < 17; ++c)
        if (c < nc)
            logits[((size_t)b * nc + c) * HW + pix] = fmaf(6.f, v[c], -ss - 9.f);
    float* f = feats + ((size_t)b * HW + pix) * nc;
#pragma unroll
    for (int c = 0; c < 17; ++c)
        if (c < nc) f[c] = v[c];
}

__global__ void centers_k(float* __restrict__ c0, float* __restrict__ c1)
{
    const int t = blockIdx.x * 64 + threadIdx.x;
    if (t < 256) c0[t] = (t / 16 == t % 16) ? 3.f : 0.f;
    const int u = t - 256;
    if (u >= 0 && u < 289) c1[u] = (u / 17 == u % 17) ? 3.f : 0.f;
}

// ---------------- host ----------------
extern "C" void kernel_launch(void* const* d_in, const int* in_sizes, int n_in,
                              void* d_out, int out_size, void* d_ws, size_t ws_size,
                              hipStream_t stream)
{
    const float* low_level = (const float*)d_in[0];
    const float* aspp_in   = (const float*)d_in[1];
    float* ws = (float*)d_ws;
    float* o  = (float*)d_out;

    // ---- ws layout (float offsets) ----
    float* GUARDF  = ws + 0;                          //      4,096 fl zeros
    f16*   GUARD   = (f16*)GUARDF;
    f16*   Apack2  = (f16*)(ws + 4096);               // 14,680,064 fl (2 heads); later C1O2 alias
    f16*   C1O2    = (f16*)(ws + 4096);
    f16*   AprojP2 = (f16*)(ws + 14684160);           //    262,144 fl
    f16*   Cw1P2   = (f16*)(ws + 14946304);           //    737,280 fl
    f16*   LlP2    = (f16*)(ws + 15683584);           //     32,768 fl
    f16*   Xa      = (f16*)(ws + 15716352);           //  2,230,272 fl
    f16*   BRpart  = (f16*)(ws + 17946624);           //  5,575,680 fl ([4][10][256][1089] f16)
    f16*   BRX2    = (f16*)(ws + 23522304);           //  2,230,272 fl
    f16*   YBX2    = (f16*)(ws + 25752576);           //    557,568 fl
    float* XB2     = ws + 26310144;                   //  1,098,306 fl
    float* GP      = ws + 27408450;                   //      4,096 fl
    float* GPC2    = ws + 27412546;                   //      1,024 fl
    float* GPR2    = ws + 27413570;                   //      1,024 fl

    // ---- d_out scratch (overwritten by final outputs afterwards) ----
    f16*   CCX2    = (f16*)(o + 0);                   // 21.3M halves
    f16*   Xll     = (f16*)(o + 10650240);            //  8.52M halves

    const long C0o = 17369154, C1oo = 17369410;

    // 1: input transposes + global pool tail
    tcz_k<<<16912, TPB, 0, stream>>>(aspp_in, low_level, Xa, Xll, GP);
    // 2-3: pool-branch GEMVs
    gemv1_k<<<64, TPB, 0, stream>>>(
        (const float*)d_in[2 + 5], (const float*)d_in[2 + 10 + 5], GP, GPR2);
    gemv2_k<<<64, TPB, 0, stream>>>(
        (const float*)d_in[2 + 6], (const float*)d_in[2 + 10 + 6], GPR2, GPC2);

    // 4: mega pack (+ guard zero)
    PackParams P;
    int start = 0;
    for (int h = 0; h < 2; ++h) {
        const float* pw    = (const float*)d_in[2 + h * 10 + 0];
        const float* w0    = (const float*)d_in[2 + h * 10 + 1];
        const float* w1    = (const float*)d_in[2 + h * 10 + 2];
        const float* w2    = (const float*)d_in[2 + h * 10 + 3];
        const float* w3    = (const float*)d_in[2 + h * 10 + 4];
        const float* aproj = (const float*)d_in[2 + h * 10 + 6];
        const float* cw1   = (const float*)d_in[2 + h * 10 + 7];
        f16* Ap = Apack2 + (long)h * 14680064;
        const PackJob jobs[7] = {
            { w0,    Ap,                          256, 2048, 2048, 1, 256, 32, 0 },
            { w1,    Ap + 524288,                 256, 2048, 2048, 9, 256, 32, 0 },
            { w2,    Ap + 5242880,                256, 2048, 2048, 9, 256, 32, 0 },
            { w3,    Ap + 9961472,                256, 2048, 2048, 9, 256, 32, 0 },
            { aproj, AprojP2 + (long)h * 262144,  256, 1024, 1280, 1, 256, 16, 0 },
            { cw1,   Cw1P2 + (long)h * 737280,    256,  304,  304, 9, 256,  5, 0 },
            { pw,    LlP2 + (long)h * 32768,       48,  256,  256, 1, 128,  4, 0 },
        };
        for (int t = 0; t < 7; ++t) {
            P.j[h * 7 + t] = jobs[t];
            P.j[h * 7 + t].start = start;
            start += jobs[t].KB * (jobs[t].coP / 16);
        }
    }
    packw_mega<<<4833, TPB, 0, stream>>>(P, GUARDF);

    // 5: merged ASPP (z=10 row-groups, 720) + low-level conv (524) = 1244 blocks
    mconv2_k<<<1244, TPB, 0, stream>>>(Xa, Xll, Apack2, LlP2, GUARD, BRpart, CCX2);
    // 6: band-gated sum + relu + transpose -> BRX2
    tcr_k<<<dim3(35, 32, 4), TPB, 0, stream>>>(BRpart, BRX2);
    // 7: aproj 1x1, full-K, bias+relu, f16 pixel-major -> YBX2
    mconv<3, 1, 1><<<72, TPB, 0, stream>>>(
        BRX2, AprojP2, GUARD, YBX2, GPC2, 1024, 256, 33, 33, 1, 1,
        16, 1, 2230272L, 262144L, 557568L, 278784L, 256, 256, 2, 4, 1);
    // 8: upsample -> CCX2 cols 48..303 + pad-zero 304..319
    ups2pad_k<<<8841, TPB, 0, stream>>>(YBX2, CCX2);
    // 9: cw1 3x3, full-K reg accumulation, f16+relu store
    mconv<1, 1, 0><<<1048, TPB, 0, stream>>>(
        CCX2, Cw1P2, GUARD, C1O2, nullptr, 320, 256, 129, 129, 3, 1,
        5, 9, 10650240L, 737280L, 8520192L, 4260096L, 256, 0, 2, 4, 1);
    // 10: cw2 both heads
    conv1x1_m<<<dim3(66, 2, 2), TPB, 0, stream>>>(C1O2,
        (const float*)d_in[2 + 8], (const float*)d_in[2 + 10 + 8],
        (const float*)d_in[2 + 9], (const float*)d_in[2 + 10 + 9], XB2);
    // 11: final both heads
    final_m<<<4113, TPB, 0, stream>>>(XB2, o);
    // 12: centers
    centers_k<<<9, 64, 0, stream>>>(o + C0o, o + C1oo);
}

// Round 15
// 635.219 us; speedup vs baseline: 1.1872x; 1.1872x over previous
//
#include <hip/hip_runtime.h>

#define TPB 256

typedef _Float16 f16;
typedef __attribute__((ext_vector_type(8))) _Float16 f16x8;
typedef __attribute__((ext_vector_type(16))) float f32x16;

#define GLD_LDS(g, l) __builtin_amdgcn_global_load_lds( \
    (const __attribute__((address_space(1))) void*)(g), \
    (__attribute__((address_space(3))) void*)(l), 16, 0, 0)

// ---------- merged transpose-cvt (aspp + low_level) ----------
__global__ __launch_bounds__(TPB)
void tcz_k(const float* __restrict__ aspp, const float* __restrict__ ll,
           f16* __restrict__ Xa, f16* __restrict__ Xll)
{
    const int bid = blockIdx.x;
    const int tid = threadIdx.x;
    const float* src; f16* dst; int C, HW, ldk, pT, cT, bb;
    if (bid < 4480) {
        src = aspp; dst = Xa; C = 2048; HW = 1089; ldk = 2048;
        pT = bid % 35; cT = (bid / 35) % 64; bb = bid / 2240;
    } else {
        const int b2 = bid - 4480;
        src = ll; dst = Xll; C = 256; HW = 16641; ldk = 256;
        pT = b2 % 521; cT = (b2 / 521) % 8; bb = b2 / 4168;
    }
    __shared__ float t32[32 * 33];
#pragma unroll
    for (int pass = 0; pass < 4; ++pass) {
        const int ch = tid / 32 + pass * 8;
        const int px = tid % 32;
        const int c = cT * 32 + ch, p = pT * 32 + px;
        float v = 0.f;
        if (c < C && p < HW) v = src[((long)bb * C + c) * HW + p];
        t32[ch * 33 + px] = v;
    }
    __syncthreads();
#pragma unroll
    for (int pass = 0; pass < 4; ++pass) {
        const int px = tid / 32 + pass * 8;
        const int ch = tid % 32;
        const int p = pT * 32 + px, c = cT * 32 + ch;
        if (p < HW && c < C)
            dst[((long)bb * HW + p) * ldk + c] = (f16)t32[ch * 33 + px];
    }
}

// ---------- band-aware partial-sum + relu + transpose: BRpart -> BRX2 ----------
__global__ __launch_bounds__(TPB)
void tcr_k(const f16* __restrict__ part, f16* __restrict__ dst)
{
    __shared__ float t32[32 * 33];
    const int pT = blockIdx.x, cT = blockIdx.y, bb = blockIdx.z;
    const int tid = threadIdx.x;
    const int br = cT >> 3;
    const f16* pb = part + (long)bb * 2787840;
#pragma unroll
    for (int pass = 0; pass < 4; ++pass) {
        const int ch = tid / 32 + pass * 8;
        const int px = tid % 32;
        const int c = cT * 32 + ch;
        const int cl = c & 255;
        const int p = pT * 32 + px;
        float v = 0.f;
        if (p < 1089) {
            if (br == 0) {
                v = (float)pb[(long)cl * 1089 + p];
            } else {
                const int dl = 6 * br;
                const int y = p / 33;
                const int s0 = 1 + 3 * (br - 1);
#pragma unroll
                for (int g = 0; g < 3; ++g) {
                    const int dy0 = (g - 1) * dl;
                    const int yLo = max(0, -dy0), yHi = min(33, 33 - dy0);
                    if (y >= yLo && y < yHi)
                        v += (float)pb[((long)(s0 + g) * 256 + cl) * 1089 + p];
                }
            }
            v = fmaxf(v, 0.f);
        }
        t32[ch * 33 + px] = v;
    }
    __syncthreads();
#pragma unroll
    for (int pass = 0; pass < 4; ++pass) {
        const int px = tid / 32 + pass * 8;
        const int ch = tid % 32;
        const int p = pT * 32 + px, c = cT * 32 + ch;
        if (p < 1089)
            dst[((long)bb * 1089 + p) * 1024 + c] = (f16)t32[ch * 33 + px];
    }
}

// ---------- global average pool ----------
__global__ __launch_bounds__(TPB)
void gpool_k(const float* __restrict__ in, float* __restrict__ gp, int HW, float inv)
{
    const int bc = blockIdx.x;
    const float* p = in + (size_t)bc * HW;
    float s = 0.f;
    for (int i = threadIdx.x; i < HW; i += TPB) s += p[i];
#pragma unroll
    for (int off = 32; off > 0; off >>= 1) s += __shfl_down(s, off, 64);
    __shared__ float red[4];
    if ((threadIdx.x & 63) == 0) red[threadIdx.x >> 6] = s;
    __syncthreads();
    if (threadIdx.x == 0) gp[bc] = (red[0] + red[1] + red[2] + red[3]) * inv;
}

// ---------- pool-branch GEMVs ----------
__global__ __launch_bounds__(TPB)
void gemv1_k(const float* __restrict__ pw0, const float* __restrict__ pw1,
             const float* __restrict__ gp, float* __restrict__ gpr2)
{
    const int bh = blockIdx.x & 3;
    const int cgrp = blockIdx.x >> 2;
    const int b = bh & 1;
    const float* w = (bh >> 1) ? pw1 : pw0;
    const int c = cgrp * 16 + (threadIdx.x >> 4);
    const int kl = threadIdx.x & 15;
    const float* g = gp + (size_t)b * 2048;
    float4 acc = {0.f, 0.f, 0.f, 0.f};
    for (int k = kl * 4; k < 2048; k += 64) {
        const float4 wv = *(const float4*)&w[(size_t)c * 2048 + k];
        const float4 gv = *(const float4*)&g[k];
        acc.x = fmaf(wv.x, gv.x, acc.x);
        acc.y = fmaf(wv.y, gv.y, acc.y);
        acc.z = fmaf(wv.z, gv.z, acc.z);
        acc.w = fmaf(wv.w, gv.w, acc.w);
    }
    float s = (acc.x + acc.y) + (acc.z + acc.w);
#pragma unroll
    for (int o = 8; o; o >>= 1) s += __shfl_xor(s, o, 16);
    if (kl == 0) gpr2[bh * 256 + c] = fmaxf(s, 0.f);
}

__global__ __launch_bounds__(TPB)
void gemv2_k(const float* __restrict__ ap0, const float* __restrict__ ap1,
             const float* __restrict__ gpr2, float* __restrict__ gpc2)
{
    const int bh = blockIdx.x & 3;
    const int cgrp = blockIdx.x >> 2;
    const float* w = (bh >> 1) ? ap1 : ap0;
    const int c = cgrp * 16 + (threadIdx.x >> 4);
    const int kl = threadIdx.x & 15;
    const float* g = gpr2 + bh * 256;
    float4 acc = {0.f, 0.f, 0.f, 0.f};
    for (int k = kl * 4; k < 256; k += 64) {
        const float4 wv = *(const float4*)&w[(size_t)c * 1280 + 1024 + k];
        const float4 gv = *(const float4*)&g[k];
        acc.x = fmaf(wv.x, gv.x, acc.x);
        acc.y = fmaf(wv.y, gv.y, acc.y);
        acc.z = fmaf(wv.z, gv.z, acc.z);
        acc.w = fmaf(wv.w, gv.w, acc.w);
    }
    float s = (acc.x + acc.y) + (acc.z + acc.w);
#pragma unroll
    for (int o = 8; o; o >>= 1) s += __shfl_xor(s, o, 16);
    if (kl == 0) gpc2[bh * 256 + c] = s;
}

// ---------- mega pack: 14 weight-pack jobs + guard zero ----------
struct PackJob { const float* w; f16* dst; int Cout, CinUse, CinSrc, T, coP, KB, start; };
struct PackParams { PackJob j[14]; };

__global__ __launch_bounds__(TPB)
void packw_mega(PackParams P, float* __restrict__ guard)
{
    const int bid = blockIdx.x;
    const int tid = threadIdx.x;
    if (bid >= 4832) {
        float4 zv = {0.f, 0.f, 0.f, 0.f};
        float4* p = (float4*)(guard + tid * 16);
        p[0] = zv; p[1] = zv; p[2] = zv; p[3] = zv;
        return;
    }
    int ji = 0;
#pragma unroll
    for (int t = 1; t < 14; ++t) if (bid >= P.j[t].start) ji = t;
    PackJob J;
    switch (ji) {
        case 0:  J = P.j[0];  break;
        case 1:  J = P.j[1];  break;
        case 2:  J = P.j[2];  break;
        case 3:  J = P.j[3];  break;
        case 4:  J = P.j[4];  break;
        case 5:  J = P.j[5];  break;
        case 6:  J = P.j[6];  break;
        case 7:  J = P.j[7];  break;
        case 8:  J = P.j[8];  break;
        case 9:  J = P.j[9];  break;
        case 10: J = P.j[10]; break;
        case 11: J = P.j[11]; break;
        case 12: J = P.j[12]; break;
        default: J = P.j[13]; break;
    }
    const int local = bid - J.start;
    const int kb = local % J.KB;
    const int coT = local / J.KB;
    const int T = J.T;
    __shared__ float tile[16 * 577];
    const int RL = 64 * T;
    const int n = 16 * RL;
    for (int idx = tid; idx < n; idx += TPB) {
        const int row = idx / RL;
        const int jj = idx - row * RL;
        const int co = coT * 16 + row;
        const int k = kb * 64 + jj / T;
        float v = 0.f;
        if (co < J.Cout && k < J.CinUse)
            v = J.w[((long)co * J.CinSrc + kb * 64) * T + jj];
        tile[row * 577 + jj] = v;
    }
    __syncthreads();
    const int nst = 128 * T;
    for (int idx = tid; idx < nst; idx += TPB) {
        const int g = idx & 7;
        const int t = (idx >> 3) % T;
        const int co = idx / (8 * T);
        f16x8 hv;
#pragma unroll
        for (int e = 0; e < 8; ++e)
            hv[e] = (f16)tile[co * 577 + (g * 8 + e) * T + t];
        *(f16x8*)&J.dst[(((long)t * J.KB + kb) * J.coP + coT * 16 + co) * 64 + g * 8] = hv;
    }
}

// ---------- MFMA implicit-GEMM conv (R10 structure; nt-fastest decode for L2 locality) ----------
// OUTMODE: 1=f16 ch-major, 3=f16 pixel-major (ldOut). ZMAP: 0=plain, 1=ASPP z-table.
template <int OUTMODE, int ZMAP, int RELUOUT, int BIAS>
__global__ __launch_bounds__(TPB, 4)
void mconv(const f16* __restrict__ X, const f16* __restrict__ Wp,
           const f16* __restrict__ guard, void* __restrict__ out_,
           const float* __restrict__ gpc,
           int Cinp, int Cout, int H, int W, int kss_, int dl_,
           int kbPerTap, int tapCnt_,
           long xHstr, long wHstr, long oHstr, long outBStride,
           int coP, int ldOut, int NT, int NM, int NBH, int NZ)
{
    __shared__ char SH[32768];
    const int tid = threadIdx.x;

    int wg;
    {
        const int orig = blockIdx.x, nwg = gridDim.x;
        const int q = nwg >> 3, r = nwg & 7;
        const int xcd = orig & 7, off = orig >> 3;
        wg = (xcd < r ? xcd * (q + 1) : r * (q + 1) + (xcd - r) * q) + off;
    }
    // nt FASTEST: consecutive wg (same XCD chunk) share the same weight panel.
    const int nt = wg % NT; wg /= NT;
    const int mt = wg % NM; wg /= NM;
    const int bh = wg % NBH; wg /= NBH;
    const int z  = wg;  // < NZ
    const int b = bh & 1, hd = bh >> 1;
    const int co0 = mt * 128;
    const int NP = H * W;
    const long xBstr = (long)NP * Cinp;

    int kss = kss_, dl = dl_, tapStart = 0, tapCnt = tapCnt_;
    long woff = (long)hd * wHstr, ooff = (long)hd * oHstr;
    int p0 = nt * 128, pMax = NP;
    if (ZMAP == 1) {
        int br, grp;
        if (z == 0) { br = 0; grp = 1; kss = 1; dl = 1; tapStart = 0; tapCnt = 1; }
        else { br = 1 + (z - 1) / 3; grp = (z - 1) % 3;
               kss = 3; dl = (br == 1) ? 6 : (br == 2 ? 12 : 18);
               tapStart = grp * 3; tapCnt = 3; }
        woff += (br == 0) ? 0L : (br == 1 ? 524288L : (br == 2 ? 5242880L : 9961472L));
        ooff += (long)z * 278784L;                 // per-slice partial (non-atomic)
        const int dy0 = (kss == 1) ? 0 : (grp - 1) * dl;
        const int yLo = max(0, -dy0), yHi = min(H, H - dy0);
        p0 = yLo * W + nt * 128;
        pMax = yHi * W;
        if (p0 >= pMax) return;
    }
    const int half = kss >> 1;
    const int y0t = p0 / W, y1t = min(p0 + 127, pMax - 1) / W;

    int taps[9]; int nval = 0;
    for (int t = 0; t < tapCnt; ++t) {
        const int tp = tapStart + t;
        const int ky = tp / kss;
        const int dy = (ky - half) * dl;
        if (ZMAP == 1 || (y1t + dy >= 0 && y0t + dy < H)) taps[nval++] = tp;
    }
    if (nval == 0) return;

    const int srow = tid >> 3;
    const int sslot = tid & 7;
    int aofs[4];
#pragma unroll
    for (int q = 0; q < 4; ++q) {
        const int row = q * 32 + srow;
        aofs[q] = row * 64 + ((sslot ^ (row & 7)) << 3);
    }
    const long coStr = (long)coP * 64;

    const int lane = tid & 63, wid = tid >> 6;
    const int wm = wid >> 1, wn = wid & 1;
    const int r32 = lane & 31, hh = lane >> 5;
    const int arow0 = wm * 64 + r32, arow1 = arow0 + 32;
    const int brow0 = wn * 64 + r32, brow1 = brow0 + 32;
    const int abase0 = arow0 * 128, abase1 = arow1 * 128;
    const int bbase0 = 16384 + brow0 * 128, bbase1 = 16384 + brow1 * 128;
    const int ax0 = (arow0 & 7), ax1 = (arow1 & 7);
    const int bx0 = (brow0 & 7), bx1 = (brow1 & 7);

    f32x16 acc[2][2];
#pragma unroll
    for (int i = 0; i < 2; ++i)
#pragma unroll
        for (int j = 0; j < 2; ++j) acc[i][j] = (f32x16)(0.f);

    const f16* Pr[4];
    for (int ti = 0; ti < nval; ++ti) {
        const int tp = taps[ti];
        const int ky = tp / kss, kx = tp - ky * kss;
        const int dy = (ky - half) * dl, dx = (kx - half) * dl;
#pragma unroll
        for (int q = 0; q < 4; ++q) {
            const int row = q * 32 + srow;
            const int p = p0 + row;
            bool v = p < pMax;
            const int py = v ? p / W : 0;
            const int px = v ? p - py * W : 0;
            const int sy = py + dy, sx = px + dx;
            v = v && ((unsigned)sy < (unsigned)H) && ((unsigned)sx < (unsigned)W);
            const int swz = (sslot ^ (row & 7)) << 3;
            Pr[q] = v ? (X + (long)b * xBstr + (long)hd * xHstr
                           + ((long)sy * W + sx) * (long)Cinp + swz)
                      : (guard + swz);
        }
        const f16* Wt = Wp + woff + ((long)tp * kbPerTap * coP + (long)co0) * 64;
        for (int kb = 0; kb < kbPerTap; ++kb) {
            __syncthreads();
            const f16* wsrc = Wt + (long)kb * coStr;
            const long kcol = (long)kb << 6;
            GLD_LDS(wsrc + aofs[0], SH + (tid << 4));
            GLD_LDS(wsrc + aofs[1], SH + 4096 + (tid << 4));
            GLD_LDS(wsrc + aofs[2], SH + 8192 + (tid << 4));
            GLD_LDS(wsrc + aofs[3], SH + 12288 + (tid << 4));
            GLD_LDS(Pr[0] + kcol, SH + 16384 + (tid << 4));
            GLD_LDS(Pr[1] + kcol, SH + 20480 + (tid << 4));
            GLD_LDS(Pr[2] + kcol, SH + 24576 + (tid << 4));
            GLD_LDS(Pr[3] + kcol, SH + 28672 + (tid << 4));
            __syncthreads();
            __builtin_amdgcn_s_setprio(1);
#pragma unroll
            for (int kh = 0; kh < 4; ++kh) {
                const int g = kh * 2 + hh;
                const f16x8 a0 = *(const f16x8*)(SH + abase0 + ((g ^ ax0) << 4));
                const f16x8 a1 = *(const f16x8*)(SH + abase1 + ((g ^ ax1) << 4));
                const f16x8 b0 = *(const f16x8*)(SH + bbase0 + ((g ^ bx0) << 4));
                const f16x8 b1 = *(const f16x8*)(SH + bbase1 + ((g ^ bx1) << 4));
                acc[0][0] = __builtin_amdgcn_mfma_f32_32x32x16_f16(a0, b0, acc[0][0], 0, 0, 0);
                acc[0][1] = __builtin_amdgcn_mfma_f32_32x32x16_f16(a0, b1, acc[0][1], 0, 0, 0);
                acc[1][0] = __builtin_amdgcn_mfma_f32_32x32x16_f16(a1, b0, acc[1][0], 0, 0, 0);
                acc[1][1] = __builtin_amdgcn_mfma_f32_32x32x16_f16(a1, b1, acc[1][1], 0, 0, 0);
            }
            __builtin_amdgcn_s_setprio(0);
        }
    }

    const long outB = (long)b * outBStride + ooff;
    const float* gpcp = BIAS ? (gpc + (long)(b + 2 * hd) * 256) : nullptr;
#pragma unroll
    for (int mi = 0; mi < 2; ++mi)
#pragma unroll
    for (int ni = 0; ni < 2; ++ni)
#pragma unroll
    for (int j = 0; j < 16; ++j) {
        const int m = wm * 64 + mi * 32 + 4 * hh + (j & 3) + 8 * (j >> 2);
        const int n = wn * 64 + ni * 32 + r32;
        const int co = co0 + m;
        const int p = p0 + n;
        if (co < Cout && p < pMax) {
            float v = acc[mi][ni][j];
            if (BIAS) v += gpcp[co];
            if (RELUOUT) v = fmaxf(v, 0.f);
            if (OUTMODE == 1) ((f16*)out_)[outB + (long)co * NP + p] = (f16)v;
            else              ((f16*)out_)[outB + (long)p * ldOut + co] = (f16)v;
        }
    }
}

// ---------- upsample 33->129 (4 slots) + CCX2 pad-zero ----------
__global__ __launch_bounds__(TPB)
void ups2pad_k(const f16* __restrict__ ybx, f16* __restrict__ ccx)
{
    const int idx = blockIdx.x * TPB + threadIdx.x;
    if (idx >= 4 * 16641 * 34) return;
    const int s = idx / (16641 * 34);
    const int rem = idx - s * (16641 * 34);
    const int p = rem / 34;
    const int cg = rem - p * 34;
    if (cg >= 32) {
        f16x8 zv = (f16x8)(f16)0.f;
        *(f16x8*)(ccx + ((long)s * 16641 + p) * 320 + 304 + (cg - 32) * 8) = zv;
        return;
    }
    const int oy = p / 129, ox = p % 129;
    const float sc = 33.0f / 129.0f;
    const float sx = (ox + 0.5f) * sc - 0.5f;
    const float sy = (oy + 0.5f) * sc - 0.5f;
    int ix0 = (int)floorf(sx), iy0 = (int)floorf(sy);
    const float fx = sx - ix0, fy = sy - iy0;
    int ix1 = min(32, max(0, ix0 + 1)); ix0 = min(32, max(0, ix0));
    int iy1 = min(32, max(0, iy0 + 1)); iy0 = min(32, max(0, iy0));
    const f16* base = ybx + (long)s * 1089 * 256 + cg * 8;
    const f16x8 v00 = *(const f16x8*)(base + ((long)iy0 * 33 + ix0) * 256);
    const f16x8 v01 = *(const f16x8*)(base + ((long)iy0 * 33 + ix1) * 256);
    const f16x8 v10 = *(const f16x8*)(base + ((long)iy1 * 33 + ix0) * 256);
    const f16x8 v11 = *(const f16x8*)(base + ((long)iy1 * 33 + ix1) * 256);
    f16x8 r;
#pragma unroll
    for (int e = 0; e < 8; ++e) {
        const float a0 = (float)v00[e] + ((float)v01[e] - (float)v00[e]) * fx;
        const float a1 = (float)v10[e] + ((float)v11[e] - (float)v10[e]) * fx;
        r[e] = (f16)(a0 + (a1 - a0) * fy);
    }
    *(f16x8*)(ccx + ((long)s * 16641 + p) * 320 + 48 + cg * 8) = r;
}

// ---------- cw2 1x1 conv, both heads, raw weights ----------
__global__ __launch_bounds__(TPB)
void conv1x1_m(const f16* __restrict__ c1o2,
               const float* __restrict__ w0, const float* __restrict__ w1,
               const float* __restrict__ b0, const float* __restrict__ b1,
               float* __restrict__ xb2)
{
    const int h = blockIdx.z;
    const int nc = h ? 17 : 16;
    const float* w = h ? w1 : w0;
    const float* bias = h ? b1 : b0;
    __shared__ float wsm[256 * 17];
    __shared__ float bsm[17];
    const int tid = threadIdx.x;
    for (int l = tid; l < 256 * 17; l += TPB) {
        const int k = l / 17, c = l - k * 17;
        wsm[l] = (c < nc) ? w[(size_t)c * 256 + k] : 0.f;
    }
    if (tid < nc) bsm[tid] = bias[tid];
    __syncthreads();
    const int b = blockIdx.y;
    const int p = blockIdx.x * TPB + tid;
    if (p >= 16641) return;
    const f16* inB = c1o2 + (long)h * 8520192 + (long)b * 4260096 + p;
    float acc[17];
#pragma unroll
    for (int c = 0; c < 17; ++c) acc[c] = 0.f;
    for (int k = 0; k < 256; ++k) {
        const float x = (float)inB[(size_t)k * 16641];
#pragma unroll
        for (int c = 0; c < 17; ++c) acc[c] = fmaf(wsm[k * 17 + c], x, acc[c]);
    }
    float* oB = xb2 + (h ? 532512L : 0L) + ((long)b * nc) * 16641 + p;
#pragma unroll
    for (int c = 0; c < 17; ++c)
        if (c < nc) oB[(size_t)c * 16641] = acc[c] + bsm[c];
}

// ---------- final: 129->513 bilinear + logits + NHWC features, both heads ----------
__global__ __launch_bounds__(TPB)
void final_m(const float* __restrict__ xb2, float* __restrict__ o)
{
    const int idx = blockIdx.x * TPB + threadIdx.x;
    if (idx >= 2 * 526338) return;
    const int hd = idx / 526338;
    int r = idx - hd * 526338;
    const int ox = r % 513; r /= 513;
    const int oy = r % 513;
    const int b = r / 513;
    const int nc = hd ? 17 : 16;
    const long HW = 513L * 513L;
    const float sc = 129.0f / 513.0f;
    const float sx = (ox + 0.5f) * sc - 0.5f;
    const float sy = (oy + 0.5f) * sc - 0.5f;
    int ix0 = (int)floorf(sx), iy0 = (int)floorf(sy);
    const float fx = sx - ix0, fy = sy - iy0;
    int ix1 = min(128, max(0, ix0 + 1)); ix0 = min(128, max(0, ix0));
    int iy1 = min(128, max(0, iy0 + 1)); iy0 = min(128, max(0, iy0));
    const float* xb = xb2 + (hd ? 532512L : 0L) + (size_t)b * nc * 16641;
    const int i00 = iy0 * 129 + ix0, i01 = iy0 * 129 + ix1;
    const int i10 = iy1 * 129 + ix0, i11 = iy1 * 129 + ix1;
    float* logits = o + (hd ? 8421408L : 0L);
    float* feats  = o + (hd ? 25791107L : 17369699L);
    float v[17];
    float ss = 0.f;
#pragma unroll
    for (int c = 0; c < 17; ++c) {
        if (c < nc) {
            const float* s = xb + (size_t)c * 16641;
            const float a0 = s[i00] + (s[i01] - s[i00]) * fx;
            const float a1 = s[i10] + (s[i11] - s[i10]) * fx;
            const float vv = a0 + (a1 - a0) * fy;
            v[c] = vv;
            ss = fmaf(vv, vv, ss);
        }
    }
    const long pix = (long)oy * 513 + ox;
#pragma unroll
    for (int c = 0; c < 17; ++c)
        if (c < nc)
            logits[((size_t)b * nc + c) * HW + pix] = fmaf(6.f, v[c], -ss - 9.f);
    float* f = feats + ((size_t)b * HW + pix) * nc;
#pragma unroll
    for (int c = 0; c < 17; ++c)
        if (c < nc) f[c] = v[c];
}

__global__ void centers_k(float* __restrict__ c0, float* __restrict__ c1)
{
    const int t = blockIdx.x * 64 + threadIdx.x;
    if (t < 256) c0[t] = (t / 16 == t % 16) ? 3.f : 0.f;
    const int u = t - 256;
    if (u >= 0 && u < 289) c1[u] = (u / 17 == u % 17) ? 3.f : 0.f;
}

// ---------------- host ----------------
extern "C" void kernel_launch(void* const* d_in, const int* in_sizes, int n_in,
                              void* d_out, int out_size, void* d_ws, size_t ws_size,
                              hipStream_t stream)
{
    const float* low_level = (const float*)d_in[0];
    const float* aspp_in   = (const float*)d_in[1];
    float* ws = (float*)d_ws;
    float* o  = (float*)d_out;

    // ---- ws layout (float offsets) ----
    float* GUARDF  = ws + 0;                          //      4,096 fl zeros
    f16*   GUARD   = (f16*)GUARDF;
    f16*   Apack2  = (f16*)(ws + 4096);               // 14,680,064 fl (2 heads); later C1O2 alias
    f16*   C1O2    = (f16*)(ws + 4096);
    f16*   AprojP2 = (f16*)(ws + 14684160);           //    262,144 fl
    f16*   Cw1P2   = (f16*)(ws + 14946304);           //    737,280 fl
    f16*   LlP2    = (f16*)(ws + 15683584);           //     32,768 fl
    f16*   Xa      = (f16*)(ws + 15716352);           //  2,230,272 fl
    f16*   BRpart  = (f16*)(ws + 17946624);           //  5,575,680 fl ([4][10][256][1089] f16)
    f16*   BRX2    = (f16*)(ws + 23522304);           //  2,230,272 fl
    f16*   YBX2    = (f16*)(ws + 25752576);           //    557,568 fl
    float* XB2     = ws + 26310144;                   //  1,098,306 fl
    float* GP      = ws + 27408450;                   //      4,096 fl
    float* GPC2    = ws + 27412546;                   //      1,024 fl
    float* GPR2    = ws + 27413570;                   //      1,024 fl

    // ---- d_out scratch (overwritten by final outputs afterwards) ----
    f16*   CCX2    = (f16*)(o + 0);                   // 21.3M halves
    f16*   Xll     = (f16*)(o + 10650240);            //  8.52M halves

    const long C0o = 17369154, C1oo = 17369410;

    // 1: input transposes
    tcz_k<<<12816, TPB, 0, stream>>>(aspp_in, low_level, Xa, Xll);
    // 2: global pool
    gpool_k<<<4096, TPB, 0, stream>>>(aspp_in, GP, 1089, 1.0f / 1089.0f);
    // 3-4: pool-branch GEMVs
    gemv1_k<<<64, TPB, 0, stream>>>(
        (const float*)d_in[2 + 5], (const float*)d_in[2 + 10 + 5], GP, GPR2);
    gemv2_k<<<64, TPB, 0, stream>>>(
        (const float*)d_in[2 + 6], (const float*)d_in[2 + 10 + 6], GPR2, GPC2);

    // 5: mega pack (+ guard zero)
    PackParams P;
    int start = 0;
    for (int h = 0; h < 2; ++h) {
        const float* pw    = (const float*)d_in[2 + h * 10 + 0];
        const float* w0    = (const float*)d_in[2 + h * 10 + 1];
        const float* w1    = (const float*)d_in[2 + h * 10 + 2];
        const float* w2    = (const float*)d_in[2 + h * 10 + 3];
        const float* w3    = (const float*)d_in[2 + h * 10 + 4];
        const float* aproj = (const float*)d_in[2 + h * 10 + 6];
        const float* cw1   = (const float*)d_in[2 + h * 10 + 7];
        f16* Ap = Apack2 + (long)h * 14680064;
        const PackJob jobs[7] = {
            { w0,    Ap,                          256, 2048, 2048, 1, 256, 32, 0 },
            { w1,    Ap + 524288,                 256, 2048, 2048, 9, 256, 32, 0 },
            { w2,    Ap + 5242880,                256, 2048, 2048, 9, 256, 32, 0 },
            { w3,    Ap + 9961472,                256, 2048, 2048, 9, 256, 32, 0 },
            { aproj, AprojP2 + (long)h * 262144,  256, 1024, 1280, 1, 256, 16, 0 },
            { cw1,   Cw1P2 + (long)h * 737280,    256,  304,  304, 9, 256,  5, 0 },
            { pw,    LlP2 + (long)h * 32768,       48,  256,  256, 1, 128,  4, 0 },
        };
        for (int t = 0; t < 7; ++t) {
            P.j[h * 7 + t] = jobs[t];
            P.j[h * 7 + t].start = start;
            start += jobs[t].KB * (jobs[t].coP / 16);
        }
    }
    packw_mega<<<4833, TPB, 0, stream>>>(P, GUARDF);

    // 6: fused ASPP (z=10 row-groups) -> per-slice f16 partials (NO atomics)
    mconv<1, 1, 0, 0><<<720, TPB, 0, stream>>>(
        Xa, Apack2, GUARD, BRpart, nullptr, 2048, 256, 33, 33, 3, 1,
        32, 0, 0L, 14680064L, 5575680L, 2787840L, 256, 0, 9, 2, 4, 10);
    // 7: band-gated sum + relu + transpose -> BRX2
    tcr_k<<<dim3(35, 32, 4), TPB, 0, stream>>>(BRpart, BRX2);
    // 8: aproj 1x1, full-K, bias+relu, f16 pixel-major -> YBX2
    mconv<3, 0, 1, 1><<<72, TPB, 0, stream>>>(
        BRX2, AprojP2, GUARD, YBX2, GPC2, 1024, 256, 33, 33, 1, 1,
        16, 1, 2230272L, 262144L, 557568L, 278784L, 256, 256, 9, 2, 4, 1);
    // 9: low-level 1x1 -> CCX2 cols 0..47
    mconv<3, 0, 1, 0><<<524, TPB, 0, stream>>>(
        Xll, LlP2, GUARD, CCX2, nullptr, 256, 48, 129, 129, 1, 1,
        4, 1, 0L, 32768L, 10650240L, 5325120L, 128, 320, 131, 1, 4, 1);
    // 10: upsample -> CCX2 cols 48..303 + pad-zero 304..319
    ups2pad_k<<<8841, TPB, 0, stream>>>(YBX2, CCX2);
    // 11: cw1 3x3, full-K reg accumulation, f16+relu store
    mconv<1, 0, 1, 0><<<1048, TPB, 0, stream>>>(
        CCX2, Cw1P2, GUARD, C1O2, nullptr, 320, 256, 129, 129, 3, 1,
        5, 9, 10650240L, 737280L, 8520192L, 4260096L, 256, 0, 131, 2, 4, 1);
    // 12: cw2 both heads
    conv1x1_m<<<dim3(66, 2, 2), TPB, 0, stream>>>(C1O2,
        (const float*)d_in[2 + 8], (const float*)d_in[2 + 10 + 8],
        (const float*)d_in[2 + 9], (const float*)d_in[2 + 10 + 9], XB2);
    // 13: final both heads
    final_m<<<4113, TPB, 0, stream>>>(XB2, o);
    // 14: centers
    centers_k<<<9, 64, 0, stream>>>(o + C0o, o + C1oo);
}

// Round 16
// 633.841 us; speedup vs baseline: 1.1898x; 1.0022x over previous
//
#include <hip/hip_runtime.h>

#define TPB 256

typedef _Float16 f16;
typedef __attribute__((ext_vector_type(8))) _Float16 f16x8;
typedef __attribute__((ext_vector_type(16))) float f32x16;

#define GLD_LDS(g, l) __builtin_amdgcn_global_load_lds( \
    (const __attribute__((address_space(1))) void*)(g), \
    (__attribute__((address_space(3))) void*)(l), 16, 0, 0)

// ---------- merged transpose-cvt (aspp + low_level) + global-pool tail ----------
__global__ __launch_bounds__(TPB)
void tcz_k(const float* __restrict__ aspp, const float* __restrict__ ll,
           f16* __restrict__ Xa, f16* __restrict__ Xll, float* __restrict__ gp)
{
    const int bid = blockIdx.x;
    const int tid = threadIdx.x;
    __shared__ float t32[32 * 33];
    __shared__ float red[4];
    if (bid >= 12816) {
        const int bc = bid - 12816;
        const float* p = aspp + (size_t)bc * 1089;
        float s = 0.f;
        for (int i = tid; i < 1089; i += TPB) s += p[i];
#pragma unroll
        for (int off = 32; off > 0; off >>= 1) s += __shfl_down(s, off, 64);
        if ((tid & 63) == 0) red[tid >> 6] = s;
        __syncthreads();
        if (tid == 0) gp[bc] = (red[0] + red[1] + red[2] + red[3]) * (1.0f / 1089.0f);
        return;
    }
    const float* src; f16* dst; int C, HW, ldk, pT, cT, bb;
    if (bid < 4480) {
        src = aspp; dst = Xa; C = 2048; HW = 1089; ldk = 2048;
        pT = bid % 35; cT = (bid / 35) % 64; bb = bid / 2240;
    } else {
        const int b2 = bid - 4480;
        src = ll; dst = Xll; C = 256; HW = 16641; ldk = 256;
        pT = b2 % 521; cT = (b2 / 521) % 8; bb = b2 / 4168;
    }
#pragma unroll
    for (int pass = 0; pass < 4; ++pass) {
        const int ch = tid / 32 + pass * 8;
        const int px = tid % 32;
        const int c = cT * 32 + ch, p = pT * 32 + px;
        float v = 0.f;
        if (c < C && p < HW) v = src[((long)bb * C + c) * HW + p];
        t32[ch * 33 + px] = v;
    }
    __syncthreads();
#pragma unroll
    for (int pass = 0; pass < 4; ++pass) {
        const int px = tid / 32 + pass * 8;
        const int ch = tid % 32;
        const int p = pT * 32 + px, c = cT * 32 + ch;
        if (p < HW && c < C)
            dst[((long)bb * HW + p) * ldk + c] = (f16)t32[ch * 33 + px];
    }
}

// ---------- band-aware partial-sum (20 slices, K-halved pairs) + relu + transpose ----------
// part: [bb][20][256][1089] f16; slices 2*zg, 2*zg+1 where zg = 0 (1x1) or 1+3*(br-1)+g.
__global__ __launch_bounds__(TPB)
void tcr_k(const f16* __restrict__ part, f16* __restrict__ dst)
{
    __shared__ float t32[32 * 33];
    const int pT = blockIdx.x, cT = blockIdx.y, bb = blockIdx.z;
    const int tid = threadIdx.x;
    const int br = cT >> 3;
    const f16* pb = part + (long)bb * 5575680;
#pragma unroll
    for (int pass = 0; pass < 4; ++pass) {
        const int ch = tid / 32 + pass * 8;
        const int px = tid % 32;
        const int c = cT * 32 + ch;
        const int cl = c & 255;
        const int p = pT * 32 + px;
        float v = 0.f;
        if (p < 1089) {
            const long cp = (long)cl * 1089 + p;
            if (br == 0) {
                v = (float)pb[cp] + (float)pb[278784 + cp];
            } else {
                const int dl = 6 * br;
                const int y = p / 33;
#pragma unroll
                for (int g = 0; g < 3; ++g) {
                    const int dy0 = (g - 1) * dl;
                    const int yLo = max(0, -dy0), yHi = min(33, 33 - dy0);
                    if (y >= yLo && y < yHi) {
                        const long s0 = (long)(2 * (1 + 3 * (br - 1) + g)) * 278784;
                        v += (float)pb[s0 + cp] + (float)pb[s0 + 278784 + cp];
                    }
                }
            }
            v = fmaxf(v, 0.f);
        }
        t32[ch * 33 + px] = v;
    }
    __syncthreads();
#pragma unroll
    for (int pass = 0; pass < 4; ++pass) {
        const int px = tid / 32 + pass * 8;
        const int ch = tid % 32;
        const int p = pT * 32 + px, c = cT * 32 + ch;
        if (p < 1089)
            dst[((long)bb * 1089 + p) * 1024 + c] = (f16)t32[ch * 33 + px];
    }
}

// ---------- pool-branch GEMVs ----------
__global__ __launch_bounds__(TPB)
void gemv1_k(const float* __restrict__ pw0, const float* __restrict__ pw1,
             const float* __restrict__ gp, float* __restrict__ gpr2)
{
    const int bh = blockIdx.x & 3;
    const int cgrp = blockIdx.x >> 2;
    const int b = bh & 1;
    const float* w = (bh >> 1) ? pw1 : pw0;
    const int c = cgrp * 16 + (threadIdx.x >> 4);
    const int kl = threadIdx.x & 15;
    const float* g = gp + (size_t)b * 2048;
    float4 acc = {0.f, 0.f, 0.f, 0.f};
    for (int k = kl * 4; k < 2048; k += 64) {
        const float4 wv = *(const float4*)&w[(size_t)c * 2048 + k];
        const float4 gv = *(const float4*)&g[k];
        acc.x = fmaf(wv.x, gv.x, acc.x);
        acc.y = fmaf(wv.y, gv.y, acc.y);
        acc.z = fmaf(wv.z, gv.z, acc.z);
        acc.w = fmaf(wv.w, gv.w, acc.w);
    }
    float s = (acc.x + acc.y) + (acc.z + acc.w);
#pragma unroll
    for (int o = 8; o; o >>= 1) s += __shfl_xor(s, o, 16);
    if (kl == 0) gpr2[bh * 256 + c] = fmaxf(s, 0.f);
}

__global__ __launch_bounds__(TPB)
void gemv2_k(const float* __restrict__ ap0, const float* __restrict__ ap1,
             const float* __restrict__ gpr2, float* __restrict__ gpc2)
{
    const int bh = blockIdx.x & 3;
    const int cgrp = blockIdx.x >> 2;
    const float* w = (bh >> 1) ? ap1 : ap0;
    const int c = cgrp * 16 + (threadIdx.x >> 4);
    const int kl = threadIdx.x & 15;
    const float* g = gpr2 + bh * 256;
    float4 acc = {0.f, 0.f, 0.f, 0.f};
    for (int k = kl * 4; k < 256; k += 64) {
        const float4 wv = *(const float4*)&w[(size_t)c * 1280 + 1024 + k];
        const float4 gv = *(const float4*)&g[k];
        acc.x = fmaf(wv.x, gv.x, acc.x);
        acc.y = fmaf(wv.y, gv.y, acc.y);
        acc.z = fmaf(wv.z, gv.z, acc.z);
        acc.w = fmaf(wv.w, gv.w, acc.w);
    }
    float s = (acc.x + acc.y) + (acc.z + acc.w);
#pragma unroll
    for (int o = 8; o; o >>= 1) s += __shfl_xor(s, o, 16);
    if (kl == 0) gpc2[bh * 256 + c] = s;
}

// ---------- mega pack: 14 weight-pack jobs + guard zero ----------
struct PackJob { const float* w; f16* dst; int Cout, CinUse, CinSrc, T, coP, KB, start; };
struct PackParams { PackJob j[14]; };

__global__ __launch_bounds__(TPB)
void packw_mega(PackParams P, float* __restrict__ guard)
{
    const int bid = blockIdx.x;
    const int tid = threadIdx.x;
    if (bid >= 4832) {
        float4 zv = {0.f, 0.f, 0.f, 0.f};
        float4* p = (float4*)(guard + tid * 16);
        p[0] = zv; p[1] = zv; p[2] = zv; p[3] = zv;
        return;
    }
    int ji = 0;
#pragma unroll
    for (int t = 1; t < 14; ++t) if (bid >= P.j[t].start) ji = t;
    PackJob J;
    switch (ji) {
        case 0:  J = P.j[0];  break;
        case 1:  J = P.j[1];  break;
        case 2:  J = P.j[2];  break;
        case 3:  J = P.j[3];  break;
        case 4:  J = P.j[4];  break;
        case 5:  J = P.j[5];  break;
        case 6:  J = P.j[6];  break;
        case 7:  J = P.j[7];  break;
        case 8:  J = P.j[8];  break;
        case 9:  J = P.j[9];  break;
        case 10: J = P.j[10]; break;
        case 11: J = P.j[11]; break;
        case 12: J = P.j[12]; break;
        default: J = P.j[13]; break;
    }
    const int local = bid - J.start;
    const int kb = local % J.KB;
    const int coT = local / J.KB;
    const int T = J.T;
    __shared__ float tile[16 * 577];
    const int RL = 64 * T;
    const int n = 16 * RL;
    for (int idx = tid; idx < n; idx += TPB) {
        const int row = idx / RL;
        const int jj = idx - row * RL;
        const int co = coT * 16 + row;
        const int k = kb * 64 + jj / T;
        float v = 0.f;
        if (co < J.Cout && k < J.CinUse)
            v = J.w[((long)co * J.CinSrc + kb * 64) * T + jj];
        tile[row * 577 + jj] = v;
    }
    __syncthreads();
    const int nst = 128 * T;
    for (int idx = tid; idx < nst; idx += TPB) {
        const int g = idx & 7;
        const int t = (idx >> 3) % T;
        const int co = idx / (8 * T);
        f16x8 hv;
#pragma unroll
        for (int e = 0; e < 8; ++e)
            hv[e] = (f16)tile[co * 577 + (g * 8 + e) * T + t];
        *(f16x8*)&J.dst[(((long)t * J.KB + kb) * J.coP + coT * 16 + co) * 64 + g * 8] = hv;
    }
}

// ---------- MFMA implicit-GEMM conv (nt-fastest decode; ASPP z = 20 K-halved slices) ----------
template <int OUTMODE, int ZMAP, int RELUOUT, int BIAS>
__global__ __launch_bounds__(TPB, 4)
void mconv(const f16* __restrict__ X, const f16* __restrict__ Wp,
           const f16* __restrict__ guard, void* __restrict__ out_,
           const float* __restrict__ gpc,
           int Cinp, int Cout, int H, int W, int kss_, int dl_,
           int kbPerTap, int tapCnt_,
           long xHstr, long wHstr, long oHstr, long outBStride,
           int coP, int ldOut, int NT, int NM, int NBH, int NZ)
{
    __shared__ char SH[32768];
    const int tid = threadIdx.x;

    int wg;
    {
        const int orig = blockIdx.x, nwg = gridDim.x;
        const int q = nwg >> 3, r = nwg & 7;
        const int xcd = orig & 7, off = orig >> 3;
        wg = (xcd < r ? xcd * (q + 1) : r * (q + 1) + (xcd - r) * q) + off;
    }
    const int nt = wg % NT; wg /= NT;
    const int mt = wg % NM; wg /= NM;
    const int bh = wg % NBH; wg /= NBH;
    const int z  = wg;  // < NZ
    const int b = bh & 1, hd = bh >> 1;
    const int co0 = mt * 128;
    const int NP = H * W;
    const long xBstr = (long)NP * Cinp;

    int kss = kss_, dl = dl_, tapStart = 0, tapCnt = tapCnt_;
    int kbB = 0, kbE = kbPerTap;
    long woff = (long)hd * wHstr, ooff = (long)hd * oHstr;
    int p0 = nt * 128, pMax = NP;
    if (ZMAP == 1) {
        const int zg = z >> 1, khf = z & 1;
        int br, grp;
        if (zg == 0) { br = 0; grp = 1; kss = 1; dl = 1; tapStart = 0; tapCnt = 1; }
        else { br = 1 + (zg - 1) / 3; grp = (zg - 1) % 3;
               kss = 3; dl = (br == 1) ? 6 : (br == 2 ? 12 : 18);
               tapStart = grp * 3; tapCnt = 3; }
        woff += (br == 0) ? 0L : (br == 1 ? 524288L : (br == 2 ? 5242880L : 9961472L));
        ooff += (long)z * 278784L;                 // per-slice partial (non-atomic)
        kbB = khf * (kbPerTap >> 1);
        kbE = kbB + (kbPerTap >> 1);
        const int dy0 = (kss == 1) ? 0 : (grp - 1) * dl;
        const int yLo = max(0, -dy0), yHi = min(H, H - dy0);
        p0 = yLo * W + nt * 128;
        pMax = yHi * W;
        if (p0 >= pMax) return;
    }
    const int half = kss >> 1;
    const int y0t = p0 / W, y1t = min(p0 + 127, pMax - 1) / W;

    int taps[9]; int nval = 0;
    for (int t = 0; t < tapCnt; ++t) {
        const int tp = tapStart + t;
        const int ky = tp / kss;
        const int dy = (ky - half) * dl;
        if (ZMAP == 1 || (y1t + dy >= 0 && y0t + dy < H)) taps[nval++] = tp;
    }
    if (nval == 0) return;

    const int srow = tid >> 3;
    const int sslot = tid & 7;
    int aofs[4];
#pragma unroll
    for (int q = 0; q < 4; ++q) {
        const int row = q * 32 + srow;
        aofs[q] = row * 64 + ((sslot ^ (row & 7)) << 3);
    }
    const long coStr = (long)coP * 64;

    const int lane = tid & 63, wid = tid >> 6;
    const int wm = wid >> 1, wn = wid & 1;
    const int r32 = lane & 31, hh = lane >> 5;
    const int arow0 = wm * 64 + r32, arow1 = arow0 + 32;
    const int brow0 = wn * 64 + r32, brow1 = brow0 + 32;
    const int abase0 = arow0 * 128, abase1 = arow1 * 128;
    const int bbase0 = 16384 + brow0 * 128, bbase1 = 16384 + brow1 * 128;
    const int ax0 = (arow0 & 7), ax1 = (arow1 & 7);
    const int bx0 = (brow0 & 7), bx1 = (brow1 & 7);

    f32x16 acc[2][2];
#pragma unroll
    for (int i = 0; i < 2; ++i)
#pragma unroll
        for (int j = 0; j < 2; ++j) acc[i][j] = (f32x16)(0.f);

    const f16* Pr[4];
    for (int ti = 0; ti < nval; ++ti) {
        const int tp = taps[ti];
        const int ky = tp / kss, kx = tp - ky * kss;
        const int dy = (ky - half) * dl, dx = (kx - half) * dl;
#pragma unroll
        for (int q = 0; q < 4; ++q) {
            const int row = q * 32 + srow;
            const int p = p0 + row;
            bool v = p < pMax;
            const int py = v ? p / W : 0;
            const int px = v ? p - py * W : 0;
            const int sy = py + dy, sx = px + dx;
            v = v && ((unsigned)sy < (unsigned)H) && ((unsigned)sx < (unsigned)W);
            const int swz = (sslot ^ (row & 7)) << 3;
            Pr[q] = v ? (X + (long)b * xBstr + (long)hd * xHstr
                           + ((long)sy * W + sx) * (long)Cinp + swz)
                      : (guard + swz);
        }
        const f16* Wt = Wp + woff + ((long)tp * kbPerTap * coP + (long)co0) * 64;
        for (int kb = kbB; kb < kbE; ++kb) {
            __syncthreads();
            const f16* wsrc = Wt + (long)kb * coStr;
            const long kcol = (long)kb << 6;
            GLD_LDS(wsrc + aofs[0], SH + (tid << 4));
            GLD_LDS(wsrc + aofs[1], SH + 4096 + (tid << 4));
            GLD_LDS(wsrc + aofs[2], SH + 8192 + (tid << 4));
            GLD_LDS(wsrc + aofs[3], SH + 12288 + (tid << 4));
            GLD_LDS(Pr[0] + kcol, SH + 16384 + (tid << 4));
            GLD_LDS(Pr[1] + kcol, SH + 20480 + (tid << 4));
            GLD_LDS(Pr[2] + kcol, SH + 24576 + (tid << 4));
            GLD_LDS(Pr[3] + kcol, SH + 28672 + (tid << 4));
            __syncthreads();
            __builtin_amdgcn_s_setprio(1);
#pragma unroll
            for (int kh = 0; kh < 4; ++kh) {
                const int g = kh * 2 + hh;
                const f16x8 a0 = *(const f16x8*)(SH + abase0 + ((g ^ ax0) << 4));
                const f16x8 a1 = *(const f16x8*)(SH + abase1 + ((g ^ ax1) << 4));
                const f16x8 b0 = *(const f16x8*)(SH + bbase0 + ((g ^ bx0) << 4));
                const f16x8 b1 = *(const f16x8*)(SH + bbase1 + ((g ^ bx1) << 4));
                acc[0][0] = __builtin_amdgcn_mfma_f32_32x32x16_f16(a0, b0, acc[0][0], 0, 0, 0);
                acc[0][1] = __builtin_amdgcn_mfma_f32_32x32x16_f16(a0, b1, acc[0][1], 0, 0, 0);
                acc[1][0] = __builtin_amdgcn_mfma_f32_32x32x16_f16(a1, b0, acc[1][0], 0, 0, 0);
                acc[1][1] = __builtin_amdgcn_mfma_f32_32x32x16_f16(a1, b1, acc[1][1], 0, 0, 0);
            }
            __builtin_amdgcn_s_setprio(0);
        }
    }

    const long outB = (long)b * outBStride + ooff;
    const float* gpcp = BIAS ? (gpc + (long)(b + 2 * hd) * 256) : nullptr;
#pragma unroll
    for (int mi = 0; mi < 2; ++mi)
#pragma unroll
    for (int ni = 0; ni < 2; ++ni)
#pragma unroll
    for (int j = 0; j < 16; ++j) {
        const int m = wm * 64 + mi * 32 + 4 * hh + (j & 3) + 8 * (j >> 2);
        const int n = wn * 64 + ni * 32 + r32;
        const int co = co0 + m;
        const int p = p0 + n;
        if (co < Cout && p < pMax) {
            float v = acc[mi][ni][j];
            if (BIAS) v += gpcp[co];
            if (RELUOUT) v = fmaxf(v, 0.f);
            if (OUTMODE == 1) ((f16*)out_)[outB + (long)co * NP + p] = (f16)v;
            else              ((f16*)out_)[outB + (long)p * ldOut + co] = (f16)v;
        }
    }
}

// ---------- upsample 33->129 (4 slots) + CCX2 pad-zero ----------
__global__ __launch_bounds__(TPB)
void ups2pad_k(const f16* __restrict__ ybx, f16* __restrict__ ccx)
{
    const int idx = blockIdx.x * TPB + threadIdx.x;
    if (idx >= 4 * 16641 * 34) return;
    const int s = idx / (16641 * 34);
    const int rem = idx - s * (16641 * 34);
    const int p = rem / 34;
    const int cg = rem - p * 34;
    if (cg >= 32) {
        f16x8 zv = (f16x8)(f16)0.f;
        *(f16x8*)(ccx + ((long)s * 16641 + p) * 320 + 304 + (cg - 32) * 8) = zv;
        return;
    }
    const int oy = p / 129, ox = p % 129;
    const float sc = 33.0f / 129.0f;
    const float sx = (ox + 0.5f) * sc - 0.5f;
    const float sy = (oy + 0.5f) * sc - 0.5f;
    int ix0 = (int)floorf(sx), iy0 = (int)floorf(sy);
    const float fx = sx - ix0, fy = sy - iy0;
    int ix1 = min(32, max(0, ix0 + 1)); ix0 = min(32, max(0, ix0));
    int iy1 = min(32, max(0, iy0 + 1)); iy0 = min(32, max(0, iy0));
    const f16* base = ybx + (long)s * 1089 * 256 + cg * 8;
    const f16x8 v00 = *(const f16x8*)(base + ((long)iy0 * 33 + ix0) * 256);
    const f16x8 v01 = *(const f16x8*)(base + ((long)iy0 * 33 + ix1) * 256);
    const f16x8 v10 = *(const f16x8*)(base + ((long)iy1 * 33 + ix0) * 256);
    const f16x8 v11 = *(const f16x8*)(base + ((long)iy1 * 33 + ix1) * 256);
    f16x8 r;
#pragma unroll
    for (int e = 0; e < 8; ++e) {
        const float a0 = (float)v00[e] + ((float)v01[e] - (float)v00[e]) * fx;
        const float a1 = (float)v10[e] + ((float)v11[e] - (float)v10[e]) * fx;
        r[e] = (f16)(a0 + (a1 - a0) * fy);
    }
    *(f16x8*)(ccx + ((long)s * 16641 + p) * 320 + 48 + cg * 8) = r;
}

// ---------- cw2 1x1 conv, both heads, raw weights ----------
__global__ __launch_bounds__(TPB)
void conv1x1_m(const f16* __restrict__ c1o2,
               const float* __restrict__ w0, const float* __restrict__ w1,
               const float* __restrict__ b0, const float* __restrict__ b1,
               float* __restrict__ xb2)
{
    const int h = blockIdx.z;
    const int nc = h ? 17 : 16;
    const float* w = h ? w1 : w0;
    const float* bias = h ? b1 : b0;
    __shared__ float wsm[256 * 17];
    __shared__ float bsm[17];
    const int tid = threadIdx.x;
    for (int l = tid; l < 256 * 17; l += TPB) {
        const int k = l / 17, c = l - k * 17;
        wsm[l] = (c < nc) ? w[(size_t)c * 256 + k] : 0.f;
    }
    if (tid < nc) bsm[tid] = bias[tid];
    __syncthreads();
    const int b = blockIdx.y;
    const int p = blockIdx.x * TPB + tid;
    if (p >= 16641) return;
    const f16* inB = c1o2 + (long)h * 8520192 + (long)b * 4260096 + p;
    float acc[17];
#pragma unroll
    for (int c = 0; c < 17; ++c) acc[c] = 0.f;
    for (int k = 0; k < 256; ++k) {
        const float x = (float)inB[(size_t)k * 16641];
#pragma unroll
        for (int c = 0; c < 17; ++c) acc[c] = fmaf(wsm[k * 17 + c], x, acc[c]);
    }
    float* oB = xb2 + (h ? 532512L : 0L) + ((long)b * nc) * 16641 + p;
#pragma unroll
    for (int c = 0; c < 17; ++c)
        if (c < nc) oB[(size_t)c * 16641] = acc[c] + bsm[c];
}

// ---------- final: 129->513 bilinear + logits + NHWC features, both heads ----------
__global__ __launch_bounds__(TPB)
void final_m(const float* __restrict__ xb2, float* __restrict__ o)
{
    const int idx = blockIdx.x * TPB + threadIdx.x;
    if (idx >= 2 * 526338) return;
    const int hd = idx / 526338;
    int r = idx - hd * 526338;
    const int ox = r % 513; r /= 513;
    const int oy = r % 513;
    const int b = r / 513;
    const int nc = hd ? 17 : 16;
    const long HW = 513L * 513L;
    const float sc = 129.0f / 513.0f;
    const float sx = (ox + 0.5f) * sc - 0.5f;
    const float sy = (oy + 0.5f) * sc - 0.5f;
    int ix0 = (int)floorf(sx), iy0 = (int)floorf(sy);
    const float fx = sx - ix0, fy = sy - iy0;
    int ix1 = min(128, max(0, ix0 + 1)); ix0 = min(128, max(0, ix0));
    int iy1 = min(128, max(0, iy0 + 1)); iy0 = min(128, max(0, iy0));
    const float* xb = xb2 + (hd ? 532512L : 0L) + (size_t)b * nc * 16641;
    const int i00 = iy0 * 129 + ix0, i01 = iy0 * 129 + ix1;
    const int i10 = iy1 * 129 + ix0, i11 = iy1 * 129 + ix1;
    float* logits = o + (hd ? 8421408L : 0L);
    float* feats  = o + (hd ? 25791107L : 17369699L);
    float v[17];
    float ss = 0.f;
#pragma unroll
    for (int c = 0; c < 17; ++c) {
        if (c < nc) {
            const float* s = xb + (size_t)c * 16641;
            const float a0 = s[i00] + (s[i01] - s[i00]) * fx;
            const float a1 = s[i10] + (s[i11] - s[i10]) * fx;
            const float vv = a0 + (a1 - a0) * fy;
            v[c] = vv;
            ss = fmaf(vv, vv, ss);
        }
    }
    const long pix = (long)oy * 513 + ox;
#pragma unroll
    for (int c = 0; c < 17; ++c)
        if (c < nc)
            logits[((size_t)b * nc + c) * HW + pix] = fmaf(6.f, v[c], -ss - 9.f);
    float* f = feats + ((size_t)b * HW + pix) * nc;
#pragma unroll
    for (int c = 0; c < 17; ++c)
        if (c < nc) f[c] = v[c];
}

__global__ void centers_k(float* __restrict__ c0, float* __restrict__ c1)
{
    const int t = blockIdx.x * 64 + threadIdx.x;
    if (t < 256) c0[t] = (t / 16 == t % 16) ? 3.f : 0.f;
    const int u = t - 256;
    if (u >= 0 && u < 289) c1[u] = (u / 17 == u % 17) ? 3.f : 0.f;
}

// ---------------- host ----------------
extern "C" void kernel_launch(void* const* d_in, const int* in_sizes, int n_in,
                              void* d_out, int out_size, void* d_ws, size_t ws_size,
                              hipStream_t stream)
{
    const float* low_level = (const float*)d_in[0];
    const float* aspp_in   = (const float*)d_in[1];
    float* ws = (float*)d_ws;
    float* o  = (float*)d_out;

    // ---- ws layout (float offsets) ----
    float* GUARDF  = ws + 0;                          //      4,096 fl zeros
    f16*   GUARD   = (f16*)GUARDF;
    f16*   Apack2  = (f16*)(ws + 4096);               // 14,680,064 fl (2 heads); later C1O2 alias
    f16*   C1O2    = (f16*)(ws + 4096);
    f16*   AprojP2 = (f16*)(ws + 14684160);           //    262,144 fl
    f16*   Cw1P2   = (f16*)(ws + 14946304);           //    737,280 fl
    f16*   LlP2    = (f16*)(ws + 15683584);           //     32,768 fl
    f16*   Xa      = (f16*)(ws + 15716352);           //  2,230,272 fl
    f16*   BRX2    = (f16*)(ws + 17946624);           //  2,230,272 fl
    f16*   YBX2    = (f16*)(ws + 20176896);           //    557,568 fl
    float* XB2     = ws + 20734464;                   //  1,098,306 fl
    float* GP      = ws + 21832770;                   //      4,096 fl
    float* GPC2    = ws + 21836866;                   //      1,024 fl
    float* GPR2    = ws + 21837890;                   //      1,024 fl

    // ---- d_out scratch (overwritten by final outputs afterwards) ----
    f16*   CCX2    = (f16*)(o + 0);                   // 21,300,480 f16
    f16*   Xll     = (f16*)(o + 10650240);            //  8,520,192 f16
    f16*   BRpart  = (f16*)(o + 14910336);            // 22,302,720 f16 ([4][20][256][1089])

    const long C0o = 17369154, C1oo = 17369410;

    // 1: input transposes + global pool tail
    tcz_k<<<16912, TPB, 0, stream>>>(aspp_in, low_level, Xa, Xll, GP);
    // 2-3: pool-branch GEMVs
    gemv1_k<<<64, TPB, 0, stream>>>(
        (const float*)d_in[2 + 5], (const float*)d_in[2 + 10 + 5], GP, GPR2);
    gemv2_k<<<64, TPB, 0, stream>>>(
        (const float*)d_in[2 + 6], (const float*)d_in[2 + 10 + 6], GPR2, GPC2);

    // 4: mega pack (+ guard zero)
    PackParams P;
    int start = 0;
    for (int h = 0; h < 2; ++h) {
        const float* pw    = (const float*)d_in[2 + h * 10 + 0];
        const float* w0    = (const float*)d_in[2 + h * 10 + 1];
        const float* w1    = (const float*)d_in[2 + h * 10 + 2];
        const float* w2    = (const float*)d_in[2 + h * 10 + 3];
        const float* w3    = (const float*)d_in[2 + h * 10 + 4];
        const float* aproj = (const float*)d_in[2 + h * 10 + 6];
        const float* cw1   = (const float*)d_in[2 + h * 10 + 7];
        f16* Ap = Apack2 + (long)h * 14680064;
        const PackJob jobs[7] = {
            { w0,    Ap,                          256, 2048, 2048, 1, 256, 32, 0 },
            { w1,    Ap + 524288,                 256, 2048, 2048, 9, 256, 32, 0 },
            { w2,    Ap + 5242880,                256, 2048, 2048, 9, 256, 32, 0 },
            { w3,    Ap + 9961472,                256, 2048, 2048, 9, 256, 32, 0 },
            { aproj, AprojP2 + (long)h * 262144,  256, 1024, 1280, 1, 256, 16, 0 },
            { cw1,   Cw1P2 + (long)h * 737280,    256,  304,  304, 9, 256,  5, 0 },
            { pw,    LlP2 + (long)h * 32768,       48,  256,  256, 1, 128,  4, 0 },
        };
        for (int t = 0; t < 7; ++t) {
            P.j[h * 7 + t] = jobs[t];
            P.j[h * 7 + t].start = start;
            start += jobs[t].KB * (jobs[t].coP / 16);
        }
    }
    packw_mega<<<4833, TPB, 0, stream>>>(P, GUARDF);

    // 5: fused ASPP (z = 20 K-halved row-group slices) -> per-slice f16 partials, 1440 blocks
    //    BRpart layout [2*hd+b][20][256][1089]: hd stride 11151360, b stride 5575680 (f16)
    mconv<1, 1, 0, 0><<<1440, TPB, 0, stream>>>(
        Xa, Apack2, GUARD, BRpart, nullptr, 2048, 256, 33, 33, 3, 1,
        32, 0, 0L, 14680064L, 11151360L, 5575680L, 256, 0, 9, 2, 4, 20);
    // 6: band-gated pair-sum + relu + transpose -> BRX2
    tcr_k<<<dim3(35, 32, 4), TPB, 0, stream>>>(BRpart, BRX2);
    // 7: aproj 1x1, full-K, bias+relu, f16 pixel-major -> YBX2
    mconv<3, 0, 1, 1><<<72, TPB, 0, stream>>>(
        BRX2, AprojP2, GUARD, YBX2, GPC2, 1024, 256, 33, 33, 1, 1,
        16, 1, 2230272L, 262144L, 557568L, 278784L, 256, 256, 9, 2, 4, 1);
    // 8: low-level 1x1 -> CCX2 cols 0..47
    mconv<3, 0, 1, 0><<<524, TPB, 0, stream>>>(
        Xll, LlP2, GUARD, CCX2, nullptr, 256, 48, 129, 129, 1, 1,
        4, 1, 0L, 32768L, 10650240L, 5325120L, 128, 320, 131, 1, 4, 1);
    // 9: upsample -> CCX2 cols 48..303 + pad-zero 304..319
    ups2pad_k<<<8841, TPB, 0, stream>>>(YBX2, CCX2);
    // 10: cw1 3x3, full-K reg accumulation, f16+relu store
    mconv<1, 0, 1, 0><<<1048, TPB, 0, stream>>>(
        CCX2, Cw1P2, GUARD, C1O2, nullptr, 320, 256, 129, 129, 3, 1,
        5, 9, 10650240L, 737280L, 8520192L, 4260096L, 256, 0, 131, 2, 4, 1);
    // 11: cw2 both heads
    conv1x1_m<<<dim3(66, 2, 2), TPB, 0, stream>>>(C1O2,
        (const float*)d_in[2 + 8], (const float*)d_in[2 + 10 + 8],
        (const float*)d_in[2 + 9], (const float*)d_in[2 + 10 + 9], XB2);
    // 12: final both heads
    final_m<<<4113, TPB, 0, stream>>>(XB2, o);
    // 13: centers
    centers_k<<<9, 64, 0, stream>>>(o + C0o, o + C1oo);
}

// Round 17
// 578.488 us; speedup vs baseline: 1.3036x; 1.0957x over previous
//
#include <hip/hip_runtime.h>

#define TPB 256

typedef _Float16 f16;
typedef __attribute__((ext_vector_type(8))) _Float16 f16x8;
typedef __attribute__((ext_vector_type(16))) float f32x16;

#define GLD_LDS(g, l) __builtin_amdgcn_global_load_lds( \
    (const __attribute__((address_space(1))) void*)(g), \
    (__attribute__((address_space(3))) void*)(l), 16, 0, 0)

// ---------- merged transpose-cvt (aspp + low_level) + global-pool tail ----------
__global__ __launch_bounds__(TPB)
void tcz_k(const float* __restrict__ aspp, const float* __restrict__ ll,
           f16* __restrict__ Xa, f16* __restrict__ Xll, float* __restrict__ gp)
{
    const int bid = blockIdx.x;
    const int tid = threadIdx.x;
    __shared__ float t32[32 * 33];
    __shared__ float red[4];
    if (bid >= 12816) {
        const int bc = bid - 12816;
        const float* p = aspp + (size_t)bc * 1089;
        float s = 0.f;
        for (int i = tid; i < 1089; i += TPB) s += p[i];
#pragma unroll
        for (int off = 32; off > 0; off >>= 1) s += __shfl_down(s, off, 64);
        if ((tid & 63) == 0) red[tid >> 6] = s;
        __syncthreads();
        if (tid == 0) gp[bc] = (red[0] + red[1] + red[2] + red[3]) * (1.0f / 1089.0f);
        return;
    }
    const float* src; f16* dst; int C, HW, ldk, pT, cT, bb;
    if (bid < 4480) {
        src = aspp; dst = Xa; C = 2048; HW = 1089; ldk = 2048;
        pT = bid % 35; cT = (bid / 35) % 64; bb = bid / 2240;
    } else {
        const int b2 = bid - 4480;
        src = ll; dst = Xll; C = 256; HW = 16641; ldk = 256;
        pT = b2 % 521; cT = (b2 / 521) % 8; bb = b2 / 4168;
    }
#pragma unroll
    for (int pass = 0; pass < 4; ++pass) {
        const int ch = tid / 32 + pass * 8;
        const int px = tid % 32;
        const int c = cT * 32 + ch, p = pT * 32 + px;
        float v = 0.f;
        if (c < C && p < HW) v = src[((long)bb * C + c) * HW + p];
        t32[ch * 33 + px] = v;
    }
    __syncthreads();
#pragma unroll
    for (int pass = 0; pass < 4; ++pass) {
        const int px = tid / 32 + pass * 8;
        const int ch = tid % 32;
        const int p = pT * 32 + px, c = cT * 32 + ch;
        if (p < HW && c < C)
            dst[((long)bb * HW + p) * ldk + c] = (f16)t32[ch * 33 + px];
    }
}

// ---------- band-aware partial-sum (20 slices, K-halved pairs) + relu + transpose ----------
__global__ __launch_bounds__(TPB)
void tcr_k(const f16* __restrict__ part, f16* __restrict__ dst)
{
    __shared__ float t32[32 * 33];
    const int pT = blockIdx.x, cT = blockIdx.y, bb = blockIdx.z;
    const int tid = threadIdx.x;
    const int br = cT >> 3;
    const f16* pb = part + (long)bb * 5575680;
#pragma unroll
    for (int pass = 0; pass < 4; ++pass) {
        const int ch = tid / 32 + pass * 8;
        const int px = tid % 32;
        const int c = cT * 32 + ch;
        const int cl = c & 255;
        const int p = pT * 32 + px;
        float v = 0.f;
        if (p < 1089) {
            const long cp = (long)cl * 1089 + p;
            if (br == 0) {
                v = (float)pb[cp] + (float)pb[278784 + cp];
            } else {
                const int dl = 6 * br;
                const int y = p / 33;
#pragma unroll
                for (int g = 0; g < 3; ++g) {
                    const int dy0 = (g - 1) * dl;
                    const int yLo = max(0, -dy0), yHi = min(33, 33 - dy0);
                    if (y >= yLo && y < yHi) {
                        const long s0 = (long)(2 * (1 + 3 * (br - 1) + g)) * 278784;
                        v += (float)pb[s0 + cp] + (float)pb[s0 + 278784 + cp];
                    }
                }
            }
            v = fmaxf(v, 0.f);
        }
        t32[ch * 33 + px] = v;
    }
    __syncthreads();
#pragma unroll
    for (int pass = 0; pass < 4; ++pass) {
        const int px = tid / 32 + pass * 8;
        const int ch = tid % 32;
        const int p = pT * 32 + px, c = cT * 32 + ch;
        if (p < 1089)
            dst[((long)bb * 1089 + p) * 1024 + c] = (f16)t32[ch * 33 + px];
    }
}

// ---------- pool-branch GEMVs ----------
__global__ __launch_bounds__(TPB)
void gemv1_k(const float* __restrict__ pw0, const float* __restrict__ pw1,
             const float* __restrict__ gp, float* __restrict__ gpr2)
{
    const int bh = blockIdx.x & 3;
    const int cgrp = blockIdx.x >> 2;
    const int b = bh & 1;
    const float* w = (bh >> 1) ? pw1 : pw0;
    const int c = cgrp * 16 + (threadIdx.x >> 4);
    const int kl = threadIdx.x & 15;
    const float* g = gp + (size_t)b * 2048;
    float4 acc = {0.f, 0.f, 0.f, 0.f};
    for (int k = kl * 4; k < 2048; k += 64) {
        const float4 wv = *(const float4*)&w[(size_t)c * 2048 + k];
        const float4 gv = *(const float4*)&g[k];
        acc.x = fmaf(wv.x, gv.x, acc.x);
        acc.y = fmaf(wv.y, gv.y, acc.y);
        acc.z = fmaf(wv.z, gv.z, acc.z);
        acc.w = fmaf(wv.w, gv.w, acc.w);
    }
    float s = (acc.x + acc.y) + (acc.z + acc.w);
#pragma unroll
    for (int o = 8; o; o >>= 1) s += __shfl_xor(s, o, 16);
    if (kl == 0) gpr2[bh * 256 + c] = fmaxf(s, 0.f);
}

__global__ __launch_bounds__(TPB)
void gemv2_k(const float* __restrict__ ap0, const float* __restrict__ ap1,
             const float* __restrict__ gpr2, float* __restrict__ gpc2)
{
    const int bh = blockIdx.x & 3;
    const int cgrp = blockIdx.x >> 2;
    const float* w = (bh >> 1) ? ap1 : ap0;
    const int c = cgrp * 16 + (threadIdx.x >> 4);
    const int kl = threadIdx.x & 15;
    const float* g = gpr2 + bh * 256;
    float4 acc = {0.f, 0.f, 0.f, 0.f};
    for (int k = kl * 4; k < 256; k += 64) {
        const float4 wv = *(const float4*)&w[(size_t)c * 1280 + 1024 + k];
        const float4 gv = *(const float4*)&g[k];
        acc.x = fmaf(wv.x, gv.x, acc.x);
        acc.y = fmaf(wv.y, gv.y, acc.y);
        acc.z = fmaf(wv.z, gv.z, acc.z);
        acc.w = fmaf(wv.w, gv.w, acc.w);
    }
    float s = (acc.x + acc.y) + (acc.z + acc.w);
#pragma unroll
    for (int o = 8; o; o >>= 1) s += __shfl_xor(s, o, 16);
    if (kl == 0) gpc2[bh * 256 + c] = s;
}

// ---------- mega pack: 14 weight-pack jobs + guard zero (float4 read path) ----------
struct PackJob { const float* w; f16* dst; int Cout, CinUse, CinSrc, T, coP, KB, start; };
struct PackParams { PackJob j[14]; };

__global__ __launch_bounds__(TPB)
void packw_mega(PackParams P, float* __restrict__ guard)
{
    const int bid = blockIdx.x;
    const int tid = threadIdx.x;
    if (bid >= 4832) {
        float4 zv = {0.f, 0.f, 0.f, 0.f};
        float4* p = (float4*)(guard + tid * 16);
        p[0] = zv; p[1] = zv; p[2] = zv; p[3] = zv;
        return;
    }
    int ji = 0;
#pragma unroll
    for (int t = 1; t < 14; ++t) if (bid >= P.j[t].start) ji = t;
    PackJob J;
    switch (ji) {
        case 0:  J = P.j[0];  break;
        case 1:  J = P.j[1];  break;
        case 2:  J = P.j[2];  break;
        case 3:  J = P.j[3];  break;
        case 4:  J = P.j[4];  break;
        case 5:  J = P.j[5];  break;
        case 6:  J = P.j[6];  break;
        case 7:  J = P.j[7];  break;
        case 8:  J = P.j[8];  break;
        case 9:  J = P.j[9];  break;
        case 10: J = P.j[10]; break;
        case 11: J = P.j[11]; break;
        case 12: J = P.j[12]; break;
        default: J = P.j[13]; break;
    }
    const int local = bid - J.start;
    const int kb = local % J.KB;
    const int coT = local / J.KB;
    const int T = J.T;
    __shared__ float tile[16 * 580];
    const int RL = 64 * T;
    if (J.CinUse != 304) {
        // vector path: full 64*T-float rows are always in-bounds for these jobs
        const int RL4 = RL >> 2;
        const int n4 = 16 * RL4;
        for (int idx = tid; idx < n4; idx += TPB) {
            const int row = idx / RL4;
            const int j4 = idx - row * RL4;
            const int co = coT * 16 + row;
            float4 v = {0.f, 0.f, 0.f, 0.f};
            if (co < J.Cout)
                v = *(const float4*)&J.w[((long)co * J.CinSrc + kb * 64) * T + j4 * 4];
            *(float4*)&tile[row * 580 + j4 * 4] = v;
        }
    } else {
        // cw1: needs per-element k < CinUse guard
        const int n = 16 * RL;
        for (int idx = tid; idx < n; idx += TPB) {
            const int row = idx / RL;
            const int jj = idx - row * RL;
            const int co = coT * 16 + row;
            const int k = kb * 64 + jj / T;
            float v = 0.f;
            if (co < J.Cout && k < J.CinUse)
                v = J.w[((long)co * J.CinSrc + kb * 64) * T + jj];
            tile[row * 580 + jj] = v;
        }
    }
    __syncthreads();
    const int nst = 128 * T;
    for (int idx = tid; idx < nst; idx += TPB) {
        const int g = idx & 7;
        const int t = (idx >> 3) % T;
        const int co = idx / (8 * T);
        f16x8 hv;
#pragma unroll
        for (int e = 0; e < 8; ++e)
            hv[e] = (f16)tile[co * 580 + (g * 8 + e) * T + t];
        *(f16x8*)&J.dst[(((long)t * J.KB + kb) * J.coP + coT * 16 + co) * 64 + g * 8] = hv;
    }
}

// ---------- MFMA implicit-GEMM conv ----------
// ZMAP: 0=plain, 1=ASPP z-table (20 K-halved slices), 2=split-K slices (z over K halves).
template <int OUTMODE, int ZMAP, int RELUOUT, int BIAS>
__global__ __launch_bounds__(TPB, 4)
void mconv(const f16* __restrict__ X, const f16* __restrict__ Wp,
           const f16* __restrict__ guard, void* __restrict__ out_,
           const float* __restrict__ gpc,
           int Cinp, int Cout, int H, int W, int kss_, int dl_,
           int kbPerTap, int tapCnt_,
           long xHstr, long wHstr, long oHstr, long outBStride, long zStr,
           int coP, int ldOut, int NT, int NM, int NBH, int NZ)
{
    __shared__ char SH[32768];
    const int tid = threadIdx.x;

    int wg;
    {
        const int orig = blockIdx.x, nwg = gridDim.x;
        const int q = nwg >> 3, r = nwg & 7;
        const int xcd = orig & 7, off = orig >> 3;
        wg = (xcd < r ? xcd * (q + 1) : r * (q + 1) + (xcd - r) * q) + off;
    }
    const int nt = wg % NT; wg /= NT;
    const int mt = wg % NM; wg /= NM;
    const int bh = wg % NBH; wg /= NBH;
    const int z  = wg;  // < NZ
    const int b = bh & 1, hd = bh >> 1;
    const int co0 = mt * 128;
    const int NP = H * W;
    const long xBstr = (long)NP * Cinp;

    int kss = kss_, dl = dl_, tapStart = 0, tapCnt = tapCnt_;
    int kbB = 0, kbE = kbPerTap;
    long woff = (long)hd * wHstr, ooff = (long)hd * oHstr;
    int p0 = nt * 128, pMax = NP;
    if (ZMAP == 1) {
        const int zg = z >> 1, khf = z & 1;
        int br, grp;
        if (zg == 0) { br = 0; grp = 1; kss = 1; dl = 1; tapStart = 0; tapCnt = 1; }
        else { br = 1 + (zg - 1) / 3; grp = (zg - 1) % 3;
               kss = 3; dl = (br == 1) ? 6 : (br == 2 ? 12 : 18);
               tapStart = grp * 3; tapCnt = 3; }
        woff += (br == 0) ? 0L : (br == 1 ? 524288L : (br == 2 ? 5242880L : 9961472L));
        ooff += (long)z * 278784L;
        kbB = khf * (kbPerTap >> 1);
        kbE = kbB + (kbPerTap >> 1);
        const int dy0 = (kss == 1) ? 0 : (grp - 1) * dl;
        const int yLo = max(0, -dy0), yHi = min(H, H - dy0);
        p0 = yLo * W + nt * 128;
        pMax = yHi * W;
        if (p0 >= pMax) return;
    } else if (ZMAP == 2) {
        kbB = z * (kbPerTap >> 1);
        kbE = kbB + (kbPerTap >> 1);
        ooff += (long)z * zStr;
    }
    const int half = kss >> 1;
    const int y0t = p0 / W, y1t = min(p0 + 127, pMax - 1) / W;

    int taps[9]; int nval = 0;
    for (int t = 0; t < tapCnt; ++t) {
        const int tp = tapStart + t;
        const int ky = tp / kss;
        const int dy = (ky - half) * dl;
        if (ZMAP == 1 || (y1t + dy >= 0 && y0t + dy < H)) taps[nval++] = tp;
    }
    if (nval == 0) return;

    const int srow = tid >> 3;
    const int sslot = tid & 7;
    int aofs[4];
#pragma unroll
    for (int q = 0; q < 4; ++q) {
        const int row = q * 32 + srow;
        aofs[q] = row * 64 + ((sslot ^ (row & 7)) << 3);
    }
    const long coStr = (long)coP * 64;

    const int lane = tid & 63, wid = tid >> 6;
    const int wm = wid >> 1, wn = wid & 1;
    const int r32 = lane & 31, hh = lane >> 5;
    const int arow0 = wm * 64 + r32, arow1 = arow0 + 32;
    const int brow0 = wn * 64 + r32, brow1 = brow0 + 32;
    const int abase0 = arow0 * 128, abase1 = arow1 * 128;
    const int bbase0 = 16384 + brow0 * 128, bbase1 = 16384 + brow1 * 128;
    const int ax0 = (arow0 & 7), ax1 = (arow1 & 7);
    const int bx0 = (brow0 & 7), bx1 = (brow1 & 7);

    f32x16 acc[2][2];
#pragma unroll
    for (int i = 0; i < 2; ++i)
#pragma unroll
        for (int j = 0; j < 2; ++j) acc[i][j] = (f32x16)(0.f);

    const f16* Pr[4];
    for (int ti = 0; ti < nval; ++ti) {
        const int tp = taps[ti];
        const int ky = tp / kss, kx = tp - ky * kss;
        const int dy = (ky - half) * dl, dx = (kx - half) * dl;
#pragma unroll
        for (int q = 0; q < 4; ++q) {
            const int row = q * 32 + srow;
            const int p = p0 + row;
            bool v = p < pMax;
            const int py = v ? p / W : 0;
            const int px = v ? p - py * W : 0;
            const int sy = py + dy, sx = px + dx;
            v = v && ((unsigned)sy < (unsigned)H) && ((unsigned)sx < (unsigned)W);
            const int swz = (sslot ^ (row & 7)) << 3;
            Pr[q] = v ? (X + (long)b * xBstr + (long)hd * xHstr
                           + ((long)sy * W + sx) * (long)Cinp + swz)
                      : (guard + swz);
        }
        const f16* Wt = Wp + woff + ((long)tp * kbPerTap * coP + (long)co0) * 64;
        for (int kb = kbB; kb < kbE; ++kb) {
            __syncthreads();
            const f16* wsrc = Wt + (long)kb * coStr;
            const long kcol = (long)kb << 6;
            GLD_LDS(wsrc + aofs[0], SH + (tid << 4));
            GLD_LDS(wsrc + aofs[1], SH + 4096 + (tid << 4));
            GLD_LDS(wsrc + aofs[2], SH + 8192 + (tid << 4));
            GLD_LDS(wsrc + aofs[3], SH + 12288 + (tid << 4));
            GLD_LDS(Pr[0] + kcol, SH + 16384 + (tid << 4));
            GLD_LDS(Pr[1] + kcol, SH + 20480 + (tid << 4));
            GLD_LDS(Pr[2] + kcol, SH + 24576 + (tid << 4));
            GLD_LDS(Pr[3] + kcol, SH + 28672 + (tid << 4));
            __syncthreads();
            __builtin_amdgcn_s_setprio(1);
#pragma unroll
            for (int kh = 0; kh < 4; ++kh) {
                const int g = kh * 2 + hh;
                const f16x8 a0 = *(const f16x8*)(SH + abase0 + ((g ^ ax0) << 4));
                const f16x8 a1 = *(const f16x8*)(SH + abase1 + ((g ^ ax1) << 4));
                const f16x8 b0 = *(const f16x8*)(SH + bbase0 + ((g ^ bx0) << 4));
                const f16x8 b1 = *(const f16x8*)(SH + bbase1 + ((g ^ bx1) << 4));
                acc[0][0] = __builtin_amdgcn_mfma_f32_32x32x16_f16(a0, b0, acc[0][0], 0, 0, 0);
                acc[0][1] = __builtin_amdgcn_mfma_f32_32x32x16_f16(a0, b1, acc[0][1], 0, 0, 0);
                acc[1][0] = __builtin_amdgcn_mfma_f32_32x32x16_f16(a1, b0, acc[1][0], 0, 0, 0);
                acc[1][1] = __builtin_amdgcn_mfma_f32_32x32x16_f16(a1, b1, acc[1][1], 0, 0, 0);
            }
            __builtin_amdgcn_s_setprio(0);
        }
    }

    const long outB = (long)b * outBStride + ooff;
    const float* gpcp = BIAS ? (gpc + (long)(b + 2 * hd) * 256) : nullptr;
#pragma unroll
    for (int mi = 0; mi < 2; ++mi)
#pragma unroll
    for (int ni = 0; ni < 2; ++ni)
#pragma unroll
    for (int j = 0; j < 16; ++j) {
        const int m = wm * 64 + mi * 32 + 4 * hh + (j & 3) + 8 * (j >> 2);
        const int n = wn * 64 + ni * 32 + r32;
        const int co = co0 + m;
        const int p = p0 + n;
        if (co < Cout && p < pMax) {
            float v = acc[mi][ni][j];
            if (BIAS && (ZMAP != 2 || z == 0)) v += gpcp[co];
            if (RELUOUT) v = fmaxf(v, 0.f);
            if (OUTMODE == 1) ((f16*)out_)[outB + (long)co * NP + p] = (f16)v;
            else              ((f16*)out_)[outB + (long)p * ldOut + co] = (f16)v;
        }
    }
}

// ---------- upsample 33->129 (sums aproj K-pair, relu) + CCX2 pad-zero ----------
__global__ __launch_bounds__(TPB)
void ups2pad_k(const f16* __restrict__ ybx, f16* __restrict__ ccx)
{
    const int idx = blockIdx.x * TPB + threadIdx.x;
    if (idx >= 4 * 16641 * 34) return;
    const int s = idx / (16641 * 34);
    const int rem = idx - s * (16641 * 34);
    const int p = rem / 34;
    const int cg = rem - p * 34;
    if (cg >= 32) {
        f16x8 zv = (f16x8)(f16)0.f;
        *(f16x8*)(ccx + ((long)s * 16641 + p) * 320 + 304 + (cg - 32) * 8) = zv;
        return;
    }
    const int oy = p / 129, ox = p % 129;
    const float sc = 33.0f / 129.0f;
    const float sx = (ox + 0.5f) * sc - 0.5f;
    const float sy = (oy + 0.5f) * sc - 0.5f;
    int ix0 = (int)floorf(sx), iy0 = (int)floorf(sy);
    const float fx = sx - ix0, fy = sy - iy0;
    int ix1 = min(32, max(0, ix0 + 1)); ix0 = min(32, max(0, ix0));
    int iy1 = min(32, max(0, iy0 + 1)); iy0 = min(32, max(0, iy0));
    const f16* base = ybx + (long)s * 278784 + cg * 8;
    const f16* base2 = base + 1115136;              // K-half slice 1
    const long i00 = ((long)iy0 * 33 + ix0) * 256;
    const long i01 = ((long)iy0 * 33 + ix1) * 256;
    const long i10 = ((long)iy1 * 33 + ix0) * 256;
    const long i11 = ((long)iy1 * 33 + ix1) * 256;
    const f16x8 a00 = *(const f16x8*)(base + i00), b00 = *(const f16x8*)(base2 + i00);
    const f16x8 a01 = *(const f16x8*)(base + i01), b01 = *(const f16x8*)(base2 + i01);
    const f16x8 a10 = *(const f16x8*)(base + i10), b10 = *(const f16x8*)(base2 + i10);
    const f16x8 a11 = *(const f16x8*)(base + i11), b11 = *(const f16x8*)(base2 + i11);
    f16x8 r;
#pragma unroll
    for (int e = 0; e < 8; ++e) {
        const float v00 = fmaxf((float)a00[e] + (float)b00[e], 0.f);
        const float v01 = fmaxf((float)a01[e] + (float)b01[e], 0.f);
        const float v10 = fmaxf((float)a10[e] + (float)b10[e], 0.f);
        const float v11 = fmaxf((float)a11[e] + (float)b11[e], 0.f);
        const float q0 = v00 + (v01 - v00) * fx;
        const float q1 = v10 + (v11 - v10) * fx;
        r[e] = (f16)(q0 + (q1 - q0) * fy);
    }
    *(f16x8*)(ccx + ((long)s * 16641 + p) * 320 + 48 + cg * 8) = r;
}

// ---------- cw2 1x1 conv, both heads, raw weights (128 threads, 524 blocks) ----------
__global__ __launch_bounds__(128)
void conv1x1_m(const f16* __restrict__ c1o2,
               const float* __restrict__ w0, const float* __restrict__ w1,
               const float* __restrict__ b0, const float* __restrict__ b1,
               float* __restrict__ xb2)
{
    const int h = blockIdx.z;
    const int nc = h ? 17 : 16;
    const float* w = h ? w1 : w0;
    const float* bias = h ? b1 : b0;
    __shared__ float wsm[256 * 17];
    __shared__ float bsm[17];
    const int tid = threadIdx.x;
    for (int l = tid; l < 256 * 17; l += 128) {
        const int k = l / 17, c = l - k * 17;
        wsm[l] = (c < nc) ? w[(size_t)c * 256 + k] : 0.f;
    }
    if (tid < nc) bsm[tid] = bias[tid];
    __syncthreads();
    const int b = blockIdx.y;
    const int p = blockIdx.x * 128 + tid;
    if (p >= 16641) return;
    const f16* inB = c1o2 + (long)h * 8520192 + (long)b * 4260096 + p;
    float acc[17];
#pragma unroll
    for (int c = 0; c < 17; ++c) acc[c] = 0.f;
    for (int k = 0; k < 256; ++k) {
        const float x = (float)inB[(size_t)k * 16641];
#pragma unroll
        for (int c = 0; c < 17; ++c) acc[c] = fmaf(wsm[k * 17 + c], x, acc[c]);
    }
    float* oB = xb2 + (h ? 532512L : 0L) + ((long)b * nc) * 16641 + p;
#pragma unroll
    for (int c = 0; c < 17; ++c)
        if (c < nc) oB[(size_t)c * 16641] = acc[c] + bsm[c];
}

// ---------- final: 129->513 bilinear + logits + NHWC features, both heads ----------
__global__ __launch_bounds__(TPB)
void final_m(const float* __restrict__ xb2, float* __restrict__ o)
{
    const int idx = blockIdx.x * TPB + threadIdx.x;
    if (idx >= 2 * 526338) return;
    const int hd = idx / 526338;
    int r = idx - hd * 526338;
    const int ox = r % 513; r /= 513;
    const int oy = r % 513;
    const int b = r / 513;
    const int nc = hd ? 17 : 16;
    const long HW = 513L * 513L;
    const float sc = 129.0f / 513.0f;
    const float sx = (ox + 0.5f) * sc - 0.5f;
    const float sy = (oy + 0.5f) * sc - 0.5f;
    int ix0 = (int)floorf(sx), iy0 = (int)floorf(sy);
    const float fx = sx - ix0, fy = sy - iy0;
    int ix1 = min(128, max(0, ix0 + 1)); ix0 = min(128, max(0, ix0));
    int iy1 = min(128, max(0, iy0 + 1)); iy0 = min(128, max(0, iy0));
    const float* xb = xb2 + (hd ? 532512L : 0L) + (size_t)b * nc * 16641;
    const int i00 = iy0 * 129 + ix0, i01 = iy0 * 129 + ix1;
    const int i10 = iy1 * 129 + ix0, i11 = iy1 * 129 + ix1;
    float* logits = o + (hd ? 8421408L : 0L);
    float* feats  = o + (hd ? 25791107L : 17369699L);
    float v[17];
    float ss = 0.f;
#pragma unroll
    for (int c = 0; c < 17; ++c) {
        if (c < nc) {
            const float* s = xb + (size_t)c * 16641;
            const float a0 = s[i00] + (s[i01] - s[i00]) * fx;
            const float a1 = s[i10] + (s[i11] - s[i10]) * fx;
            const float vv = a0 + (a1 - a0) * fy;
            v[c] = vv;
            ss = fmaf(vv, vv, ss);
        }
    }
    const long pix = (long)oy * 513 + ox;
#pragma unroll
    for (int c = 0; c < 17; ++c)
        if (c < nc)
            logits[((size_t)b * nc + c) * HW + pix] = fmaf(6.f, v[c], -ss - 9.f);
    float* f = feats + ((size_t)b * HW + pix) * nc;
#pragma unroll
    for (int c = 0; c < 17; ++c)
        if (c < nc) f[c] = v[c];
}

__global__ void centers_k(float* __restrict__ c0, float* __restrict__ c1)
{
    const int t = blockIdx.x * 64 + threadIdx.x;
    if (t < 256) c0[t] = (t / 16 == t % 16) ? 3.f : 0.f;
    const int u = t - 256;
    if (u >= 0 && u < 289) c1[u] = (u / 17 == u % 17) ? 3.f : 0.f;
}

// ---------------- host ----------------
extern "C" void kernel_launch(void* const* d_in, const int* in_sizes, int n_in,
                              void* d_out, int out_size, void* d_ws, size_t ws_size,
                              hipStream_t stream)
{
    const float* low_level = (const float*)d_in[0];
    const float* aspp_in   = (const float*)d_in[1];
    float* ws = (float*)d_ws;
    float* o  = (float*)d_out;

    // ---- ws layout (float offsets) ----
    float* GUARDF  = ws + 0;                          //      4,096 fl zeros
    f16*   GUARD   = (f16*)GUARDF;
    f16*   Apack2  = (f16*)(ws + 4096);               // 14,680,064 fl (2 heads); later C1O2 alias
    f16*   C1O2    = (f16*)(ws + 4096);
    f16*   AprojP2 = (f16*)(ws + 14684160);           //    262,144 fl
    f16*   Cw1P2   = (f16*)(ws + 14946304);           //    737,280 fl
    f16*   LlP2    = (f16*)(ws + 15683584);           //     32,768 fl
    f16*   Xa      = (f16*)(ws + 15716352);           //  2,230,272 fl
    f16*   BRX2    = (f16*)(ws + 17946624);           //  2,230,272 fl
    f16*   YBX2    = (f16*)(ws + 20176896);           //  1,115,136 fl ([2][4][1089][256] f16)
    float* XB2     = ws + 21292032;                   //  1,098,306 fl
    float* GP      = ws + 22390338;                   //      4,096 fl
    float* GPC2    = ws + 22394434;                   //      1,024 fl
    float* GPR2    = ws + 22395458;                   //      1,024 fl

    // ---- d_out scratch (overwritten by final outputs afterwards) ----
    f16*   CCX2    = (f16*)(o + 0);                   // 21,300,480 f16
    f16*   Xll     = (f16*)(o + 10650240);            //  8,520,192 f16
    f16*   BRpart  = (f16*)(o + 14910336);            // 22,302,720 f16 ([4][20][256][1089])

    const long C0o = 17369154, C1oo = 17369410;

    // 1: input transposes + global pool tail
    tcz_k<<<16912, TPB, 0, stream>>>(aspp_in, low_level, Xa, Xll, GP);
    // 2-3: pool-branch GEMVs
    gemv1_k<<<64, TPB, 0, stream>>>(
        (const float*)d_in[2 + 5], (const float*)d_in[2 + 10 + 5], GP, GPR2);
    gemv2_k<<<64, TPB, 0, stream>>>(
        (const float*)d_in[2 + 6], (const float*)d_in[2 + 10 + 6], GPR2, GPC2);

    // 4: mega pack (+ guard zero)
    PackParams P;
    int start = 0;
    for (int h = 0; h < 2; ++h) {
        const float* pw    = (const float*)d_in[2 + h * 10 + 0];
        const float* w0    = (const float*)d_in[2 + h * 10 + 1];
        const float* w1    = (const float*)d_in[2 + h * 10 + 2];
        const float* w2    = (const float*)d_in[2 + h * 10 + 3];
        const float* w3    = (const float*)d_in[2 + h * 10 + 4];
        const float* aproj = (const float*)d_in[2 + h * 10 + 6];
        const float* cw1   = (const float*)d_in[2 + h * 10 + 7];
        f16* Ap = Apack2 + (long)h * 14680064;
        const PackJob jobs[7] = {
            { w0,    Ap,                          256, 2048, 2048, 1, 256, 32, 0 },
            { w1,    Ap + 524288,                 256, 2048, 2048, 9, 256, 32, 0 },
            { w2,    Ap + 5242880,                256, 2048, 2048, 9, 256, 32, 0 },
            { w3,    Ap + 9961472,                256, 2048, 2048, 9, 256, 32, 0 },
            { aproj, AprojP2 + (long)h * 262144,  256, 1024, 1280, 1, 256, 16, 0 },
            { cw1,   Cw1P2 + (long)h * 737280,    256,  304,  304, 9, 256,  5, 0 },
            { pw,    LlP2 + (long)h * 32768,       48,  256,  256, 1, 128,  4, 0 },
        };
        for (int t = 0; t < 7; ++t) {
            P.j[h * 7 + t] = jobs[t];
            P.j[h * 7 + t].start = start;
            start += jobs[t].KB * (jobs[t].coP / 16);
        }
    }
    packw_mega<<<4833, TPB, 0, stream>>>(P, GUARDF);

    // 5: fused ASPP (z = 20 K-halved row-group slices) -> per-slice f16 partials
    mconv<1, 1, 0, 0><<<1440, TPB, 0, stream>>>(
        Xa, Apack2, GUARD, BRpart, nullptr, 2048, 256, 33, 33, 3, 1,
        32, 0, 0L, 14680064L, 11151360L, 5575680L, 0L, 256, 0, 9, 2, 4, 20);
    // 6: band-gated pair-sum + relu + transpose -> BRX2
    tcr_k<<<dim3(35, 32, 4), TPB, 0, stream>>>(BRpart, BRX2);
    // 7: aproj 1x1, split-K x2 (pre-relu pair partials; bias on slice 0) -> YBX2
    mconv<3, 2, 0, 1><<<144, TPB, 0, stream>>>(
        BRX2, AprojP2, GUARD, YBX2, GPC2, 1024, 256, 33, 33, 1, 1,
        16, 1, 2230272L, 262144L, 557568L, 278784L, 1115136L, 256, 256, 9, 2, 4, 2);
    // 8: low-level 1x1 -> CCX2 cols 0..47
    mconv<3, 0, 1, 0><<<524, TPB, 0, stream>>>(
        Xll, LlP2, GUARD, CCX2, nullptr, 256, 48, 129, 129, 1, 1,
        4, 1, 0L, 32768L, 10650240L, 5325120L, 0L, 128, 320, 131, 1, 4, 1);
    // 9: upsample (sum K-pair + relu) -> CCX2 cols 48..303 + pad-zero 304..319
    ups2pad_k<<<8841, TPB, 0, stream>>>(YBX2, CCX2);
    // 10: cw1 3x3, full-K reg accumulation, f16+relu store
    mconv<1, 0, 1, 0><<<1048, TPB, 0, stream>>>(
        CCX2, Cw1P2, GUARD, C1O2, nullptr, 320, 256, 129, 129, 3, 1,
        5, 9, 10650240L, 737280L, 8520192L, 4260096L, 0L, 256, 0, 131, 2, 4, 1);
    // 11: cw2 both heads (128-thread blocks, 2 blocks/CU)
    conv1x1_m<<<dim3(131, 2, 2), 128, 0, stream>>>(C1O2,
        (const float*)d_in[2 + 8], (const float*)d_in[2 + 10 + 8],
        (const float*)d_in[2 + 9], (const float*)d_in[2 + 10 + 9], XB2);
    // 12: final both heads
    final_m<<<4113, TPB, 0, stream>>>(XB2, o);
    // 13: centers
    centers_k<<<9, 64, 0, stream>>>(o + C0o, o + C1oo);
}